// Round 8
// baseline (643.636 us; speedup 1.0000x reference)
//
#include <hip/hip_runtime.h>
#include <math.h>

// Problem constants: b=4, c=256, heads=8, c/head=32, h=w=128, n=16384, cr=16
#define NFFT 16384
static constexpr size_t NP = 16777216; // one fp32 plane = 1024 * 16384 floats

typedef short bf16x8 __attribute__((ext_vector_type(8)));
typedef __fp16 f16x8 __attribute__((ext_vector_type(8)));
typedef float f32x4  __attribute__((ext_vector_type(4)));
typedef __fp16 h16x2 __attribute__((ext_vector_type(2)));

union FU  { bf16x8 v; unsigned u[4]; };
union FU16{ f16x8  v; unsigned u[4]; };

// ---------- helpers ----------
__device__ __forceinline__ void sincos_rev(float rv, float& sn, float& cs){
    sn = __builtin_amdgcn_sinf(rv);   // sin(2*pi*rv)
    cs = __builtin_amdgcn_cosf(rv);
}
__device__ __forceinline__ int rev7(int v){ return (int)(__brev((unsigned)v) >> 25); }

__device__ __forceinline__ unsigned f2bf(float f){
    unsigned u = __float_as_uint(f);
    return (u + 0x7FFFu + ((u >> 16) & 1u)) >> 16;   // round-to-nearest-even
}
__device__ __forceinline__ float bf2f(unsigned h){ return __uint_as_float(h << 16); }

// fp16x2 pack/unpack: packh(a,b) -> (a in LOW 16, b in HIGH 16)
union HU2 { h16x2 h; unsigned u; };
__device__ __forceinline__ unsigned packh(float a, float b){
    HU2 z; z.h = __builtin_amdgcn_cvt_pkrtz(a, b); return z.u;
}
__device__ __forceinline__ void unpackh(unsigned u, float& a, float& b){
    HU2 z; z.u = u; a = (float)z.h.x; b = (float)z.h.y;
}

// ---------- sign/identity-folded per-lane twiddles ----------
struct TwF { float cw[6], sw[6], sg[6], c6, s6; };
__device__ __forceinline__ void make_twf(TwF& t){
    const int l = threadIdx.x & 63;
    #pragma unroll
    for (int lg = 0; lg < 6; ++lg){
        int m = 1 << lg;
        bool up = (l & m) != 0;
        int e = (l & (m-1)) * (64 >> lg);
        float sn, cs; sincos_rev((float)e * 0.0078125f, sn, cs);
        t.cw[lg] = up ? cs : 1.f;
        t.sw[lg] = up ? -sn : 0.f;
        t.sg[lg] = up ? -1.f : 1.f;
    }
    sincos_rev((float)l * 0.0078125f, t.s6, t.c6);
}
// DIT (inverse), select-free: every lane multiplies SELF by folded w
// (up lane: w = e^{+2pi i e/128}, down lane: 1), shuffles the product, then
// y = shfl(q) + sg*q  (down sg=+1: x_d + w*x_u; up sg=-1: x_d - w*x_u).
struct TwI { float cw[6], sw[6], sg[6], c6, s6; };
__device__ __forceinline__ void make_twi(TwI& t){
    const int l = threadIdx.x & 63;
    #pragma unroll
    for (int lg = 0; lg < 6; ++lg){
        int m = 1 << lg;
        bool up = (l & m) != 0;
        int e = (l & (m-1)) * (64 >> lg);
        float sn, cs; sincos_rev((float)e * 0.0078125f, sn, cs);
        t.cw[lg] = up ? cs : 1.f;
        t.sw[lg] = up ? sn : 0.f;
        t.sg[lg] = up ? -1.f : 1.f;
    }
    sincos_rev((float)l * 0.0078125f, t.s6, t.c6);
}

// DIF forward: natural in, slot j holds X[rev7(j)] out. W = e^{-2pi i/128}
__device__ __forceinline__ void dif128t(const TwF& t, float& r0, float& i0, float& r1, float& i1){
    {
        float ar = r0 + r1, ai = i0 + i1;
        float br = r0 - r1, bi = i0 - i1;
        r0 = ar; i0 = ai;
        r1 =  br*t.c6 + bi*t.s6;
        i1 = -br*t.s6 + bi*t.c6;
    }
    #pragma unroll
    for (int lg = 5; lg >= 0; --lg){
        int m = 1 << lg;
        float cw = t.cw[lg], sw = t.sw[lg], sg = t.sg[lg];
        float pr = __shfl_xor(r0, m, 64), pi = __shfl_xor(i0, m, 64);
        float tr = fmaf(sg, r0, pr), ti = fmaf(sg, i0, pi);
        r0 = tr*cw - ti*sw;
        i0 = tr*sw + ti*cw;
        pr = __shfl_xor(r1, m, 64); pi = __shfl_xor(i1, m, 64);
        tr = fmaf(sg, r1, pr); ti = fmaf(sg, i1, pi);
        r1 = tr*cw - ti*sw;
        i1 = tr*sw + ti*cw;
    }
}

// DIT inverse (unnormalized): slot j holds X[rev7(j)] in, natural out. W = e^{+2pi i/128}
__device__ __forceinline__ void dit128t(const TwI& t, float& r0, float& i0, float& r1, float& i1){
    #pragma unroll
    for (int lg = 0; lg <= 5; ++lg){
        int m = 1 << lg;
        float cw = t.cw[lg], sw = t.sw[lg], sg = t.sg[lg];
        float qr = r0*cw - i0*sw, qi = r0*sw + i0*cw;
        float pr = __shfl_xor(qr, m, 64), pi = __shfl_xor(qi, m, 64);
        r0 = fmaf(sg, qr, pr);
        i0 = fmaf(sg, qi, pi);
        qr = r1*cw - i1*sw; qi = r1*sw + i1*cw;
        pr = __shfl_xor(qr, m, 64); pi = __shfl_xor(qi, m, 64);
        r1 = fmaf(sg, qr, pr);
        i1 = fmaf(sg, qi, pi);
    }
    {
        float wr = r1*t.c6 - i1*t.s6, wi = r1*t.s6 + i1*t.c6;
        float ar = r0 + wr, ai = i0 + wi;
        r1 = r0 - wr; i1 = i0 - wi;
        r0 = ar; i0 = ai;
    }
}

// ---------- K1: fused forward fft2 per image -> fp16 half-planes SpecR/SpecI ----------
__global__ __launch_bounds__(1024, 8) void k_fft2_fwd(const float* __restrict__ x,
                                                   unsigned* __restrict__ spR, unsigned* __restrict__ spI,
                                                   float* __restrict__ norm2){
    __shared__ unsigned sp[128*129];
    __shared__ float red[16];
    int lane = threadIdx.x & 63, wave = threadIdx.x >> 6;
    int img = blockIdx.x;
    TwF tw; make_twf(tw);
    const float* base = x + (size_t)img * NFFT;
    #pragma unroll 4
    for (int it = 0; it < 8; ++it){
        int h = (wave << 3) + it;
        float a0 = base[h*128 + lane], b0 = 0.f;
        float a1 = base[h*128 + lane + 64], b1 = 0.f;
        dif128t(tw, a0, b0, a1, b1);
        sp[lane*129 + h]      = packh(a0, b0);
        sp[(lane+64)*129 + h] = packh(a1, b1);
    }
    __syncthreads();
    float acc0 = 0.f, acc1 = 0.f;
    #pragma unroll 4
    for (int it = 0; it < 8; ++it){
        int j = (wave << 3) + it;
        float a0, b0, a1, b1;
        unpackh(sp[j*129 + lane],      a0, b0);
        unpackh(sp[j*129 + lane + 64], a1, b1);
        dif128t(tw, a0, b0, a1, b1);
        acc0 += a0*a0 + b0*b0;
        acc1 += a1*a1 + b1*b1;
        float t0 = __shfl_xor(a0, 1, 64), u0 = __shfl_xor(b0, 1, 64);
        float t1 = __shfl_xor(a1, 1, 64), u1 = __shfl_xor(b1, 1, 64);
        size_t m = (size_t)img*8192 + (size_t)j*64;
        int k = lane >> 1;
        if (!(lane & 1)){
            spR[m + k]      = packh(a0, t0);
            spR[m + 32 + k] = packh(a1, t1);
        } else {
            spI[m + k]      = packh(u0, b0);
            spI[m + 32 + k] = packh(u1, b1);
        }
    }
    float acc = acc0 + acc1;
    #pragma unroll
    for (int m = 32; m >= 1; m >>= 1) acc += __shfl_xor(acc, m, 64);
    if (lane == 0) red[wave] = acc;
    __syncthreads();
    if (threadIdx.x == 0){
        float s = 0.f;
        #pragma unroll
        for (int i = 0; i < 16; ++i) s += red[i];
        norm2[img] = s;
    }
}

// ---------- K2: gram via f16 MFMA, zero-conversion staging ----------
__global__ __launch_bounds__(256) void k_gram(const unsigned* __restrict__ spR, const unsigned* __restrict__ spI,
                                              float* __restrict__ Gpart){
    __shared__ unsigned lds[2*32*132];
    int t = threadIdx.x, lane = t & 63, wave = t >> 6;
    int bh = blockIdx.x >> 5;
    int ks = blockIdx.x & 31;          // 32 k-splits, K=512 each
    size_t cbase2 = (size_t)bh * 32 * 8192;
    int k0blk = ks << 9;

    int sc = t >> 3, tk = t & 7;

    f32x4 aRe[2][2], aIm[2][2];
    #pragma unroll
    for (int i = 0; i < 2; ++i)
        #pragma unroll
        for (int j = 0; j < 2; ++j){ aRe[i][j] = (f32x4){0,0,0,0}; aIm[i][j] = (f32x4){0,0,0,0}; }

    for (int tile = 0; tile < 2; ++tile){
        int kb = k0blk + (tile << 8);
        __syncthreads();
        {
            const unsigned* pr  = spR + cbase2 + (size_t)sc*8192 + (kb >> 1) + tk*16;
            const unsigned* pi_ = spI + cbase2 + (size_t)sc*8192 + (kb >> 1) + tk*16;
            unsigned* dr = &lds[sc*132 + tk*16];
            unsigned* di = &lds[32*132 + sc*132 + tk*16];
            #pragma unroll
            for (int j = 0; j < 4; ++j){
                *(uint4*)(dr + 4*j) = *(const uint4*)(pr + 4*j);
                *(uint4*)(di + 4*j) = *(const uint4*)(pi_ + 4*j);
            }
        }
        __syncthreads();
        #pragma unroll
        for (int ss = 0; ss < 2; ++ss){
            int s = wave + (ss << 2);
            int kbase = (s << 4) + ((lane >> 4) << 2);
            FU16 fr0, fr1, fi0, fi1, fn0, fn1;
            *(uint4*)fr0.u = *(const uint4*)&lds[ (lane & 15)*132 + kbase ];
            *(uint4*)fr1.u = *(const uint4*)&lds[ ((lane & 15) + 16)*132 + kbase ];
            *(uint4*)fi0.u = *(const uint4*)&lds[ 32*132 + (lane & 15)*132 + kbase ];
            *(uint4*)fi1.u = *(const uint4*)&lds[ 32*132 + ((lane & 15) + 16)*132 + kbase ];
            #pragma unroll
            for (int p = 0; p < 4; ++p){ fn0.u[p] = fi0.u[p] ^ 0x80008000u; fn1.u[p] = fi1.u[p] ^ 0x80008000u; }
            aRe[0][0] = __builtin_amdgcn_mfma_f32_16x16x32_f16(fr0.v, fr0.v, aRe[0][0], 0, 0, 0);
            aRe[0][0] = __builtin_amdgcn_mfma_f32_16x16x32_f16(fn0.v, fi0.v, aRe[0][0], 0, 0, 0);
            aRe[0][1] = __builtin_amdgcn_mfma_f32_16x16x32_f16(fr0.v, fr1.v, aRe[0][1], 0, 0, 0);
            aRe[0][1] = __builtin_amdgcn_mfma_f32_16x16x32_f16(fn0.v, fi1.v, aRe[0][1], 0, 0, 0);
            aRe[1][0] = __builtin_amdgcn_mfma_f32_16x16x32_f16(fr1.v, fr0.v, aRe[1][0], 0, 0, 0);
            aRe[1][0] = __builtin_amdgcn_mfma_f32_16x16x32_f16(fn1.v, fi0.v, aRe[1][0], 0, 0, 0);
            aRe[1][1] = __builtin_amdgcn_mfma_f32_16x16x32_f16(fr1.v, fr1.v, aRe[1][1], 0, 0, 0);
            aRe[1][1] = __builtin_amdgcn_mfma_f32_16x16x32_f16(fn1.v, fi1.v, aRe[1][1], 0, 0, 0);
            aIm[0][0] = __builtin_amdgcn_mfma_f32_16x16x32_f16(fr0.v, fi0.v, aIm[0][0], 0, 0, 0);
            aIm[0][0] = __builtin_amdgcn_mfma_f32_16x16x32_f16(fi0.v, fr0.v, aIm[0][0], 0, 0, 0);
            aIm[0][1] = __builtin_amdgcn_mfma_f32_16x16x32_f16(fr0.v, fi1.v, aIm[0][1], 0, 0, 0);
            aIm[0][1] = __builtin_amdgcn_mfma_f32_16x16x32_f16(fi0.v, fr1.v, aIm[0][1], 0, 0, 0);
            aIm[1][0] = __builtin_amdgcn_mfma_f32_16x16x32_f16(fr1.v, fi0.v, aIm[1][0], 0, 0, 0);
            aIm[1][0] = __builtin_amdgcn_mfma_f32_16x16x32_f16(fi1.v, fr0.v, aIm[1][0], 0, 0, 0);
            aIm[1][1] = __builtin_amdgcn_mfma_f32_16x16x32_f16(fr1.v, fi1.v, aIm[1][1], 0, 0, 0);
            aIm[1][1] = __builtin_amdgcn_mfma_f32_16x16x32_f16(fi1.v, fr1.v, aIm[1][1], 0, 0, 0);
        }
    }
    __syncthreads();
    float* rbuf = (float*)lds;
    int dcol = lane & 15, rrow = lane >> 4;
    #pragma unroll
    for (int i = 0; i < 2; ++i)
        #pragma unroll
        for (int j = 0; j < 2; ++j)
            #pragma unroll
            for (int r = 0; r < 4; ++r){
                int c = (i << 4) + (rrow << 2) + r;
                int d = (j << 4) + dcol;
                rbuf[wave*2048 + ((c << 5) + d)*2    ] = aRe[i][j][r];
                rbuf[wave*2048 + ((c << 5) + d)*2 + 1] = aIm[i][j][r];
            }
    __syncthreads();
    float* gp = Gpart + (size_t)blockIdx.x * 2048;
    for (int idx = t; idx < 2048; idx += 256)
        gp[idx] = rbuf[idx] + rbuf[2048 + idx] + rbuf[4096 + idx] + rbuf[6144 + idx];
}

// ---------- K2b: reduce 32 k-split partials per bh ----------
__global__ __launch_bounds__(256) void k_gram_red(const float* __restrict__ Gpart, float* __restrict__ G){
    int bh = blockIdx.x >> 3;
    int q  = ((blockIdx.x & 7) << 8) + threadIdx.x;
    const float* gp = Gpart + (size_t)bh * 32 * 2048 + q;
    float s = 0.f;
    #pragma unroll 8
    for (int p = 0; p < 32; ++p) s += gp[(size_t)p * 2048];
    G[(size_t)bh * 2048 + q] = s;
}

// ---------- K3: normalize, temperature, complex softmax, fold IF32 * (1/524288) ----------
__global__ __launch_bounds__(256) void k_attn(const float* __restrict__ G, const float* __restrict__ norm2,
                                              const float* __restrict__ temp, float* __restrict__ attn2){
    __shared__ float ar[32*33], ai[32*33];
    int bh = blockIdx.x, h = bh & 7, t = threadIdx.x;
    if (t < 32){
        float tv = temp[h];
        float nc = fmaxf(sqrtf(norm2[(bh<<5) + t]), 1e-12f);
        const float* gr = G + (size_t)bh*2048 + t*64;
        float mr = -1e30f, mi = -1e30f;
        for (int d = 0; d < 32; ++d){
            float nd = fmaxf(sqrtf(norm2[(bh<<5) + d]), 1e-12f);
            float s = tv / (nc * nd);
            float vr = gr[d*2] * s, vi = gr[d*2+1] * s;
            ar[t*33+d] = vr; ai[t*33+d] = vi;
            mr = fmaxf(mr, vr); mi = fmaxf(mi, vi);
        }
        float sr = 0.f, si = 0.f;
        for (int d = 0; d < 32; ++d){
            float er = __expf(ar[t*33+d] - mr), ei = __expf(ai[t*33+d] - mi);
            ar[t*33+d] = er; ai[t*33+d] = ei; sr += er; si += ei;
        }
        sr = 1.f/sr; si = 1.f/si;
        for (int d = 0; d < 32; ++d){ ar[t*33+d] *= sr; ai[t*33+d] *= si; }
    }
    __syncthreads();
    const float S = 1.f / 524288.f;
    for (int q = t; q < 1024; q += 256){
        int e = q >> 5, d = q & 31;
        float sr = 0.f, si = 0.f;
        for (int c = 0; c < 32; ++c){
            float sn, cs; sincos_rev((float)((e*c) & 31) * 0.03125f, sn, cs);
            float xr = ar[c*33+d], xi = ai[c*33+d];
            sr += cs*xr - sn*xi;
            si += cs*xi + sn*xr;
        }
        attn2[(size_t)bh*2048 + q*2]     = sr * S;
        attn2[(size_t)bh*2048 + q*2 + 1] = si * S;
    }
}

// ---------- K4: mix[e][n] = sum_d attn2[e][d] * X[d][n] via f16 MFMA ----------
__global__ __launch_bounds__(256) void k_mix(const unsigned* __restrict__ spR, const unsigned* __restrict__ spI,
                                             const float* __restrict__ attn2,
                                             unsigned* __restrict__ om){
    __shared__ unsigned lds[2*32*36];
    __shared__ float a2s[2048];
    int t = threadIdx.x, lane = t & 63, wave = t >> 6;
    int quad = lane >> 4, l15 = lane & 15;
    int bh = blockIdx.x >> 5;
    int n0 = (blockIdx.x & 31) << 9;
    size_t cbase2 = (size_t)bh * 32 * 8192;
    {
        const float4* s4 = (const float4*)(attn2 + (size_t)bh*2048);
        float4* d4 = (float4*)a2s;
        d4[t] = s4[t]; d4[t + 256] = s4[t + 256];
    }
    __syncthreads();
    FU16 Ar[2], Ai[2];
    #pragma unroll
    for (int et = 0; et < 2; ++et){
        int e = (et << 4) + l15;
        #pragma unroll
        for (int p = 0; p < 4; ++p){
            int d0 = (quad << 3) + (p << 1);
            Ar[et].u[p] = packh(a2s[(e*32 + d0)*2],     a2s[(e*32 + d0 + 1)*2]);
            Ai[et].u[p] = packh(a2s[(e*32 + d0)*2 + 1], a2s[(e*32 + d0 + 1)*2 + 1]);
        }
    }
    int sd = t >> 3, sc4 = (t & 7) << 2;
    for (int tile = 0; tile < 8; ++tile){
        int nb = n0 + (tile << 6);
        __syncthreads();
        {
            size_t g2 = cbase2 + (size_t)sd*8192 + (nb >> 1) + sc4;
            *(uint4*)&lds[sd*36 + sc4]         = *(const uint4*)&spR[g2];
            *(uint4*)&lds[32*36 + sd*36 + sc4] = *(const uint4*)&spI[g2];
        }
        __syncthreads();
        int colb = (wave << 4) + l15;
        int cb2 = colb >> 1; bool codd = colb & 1;
        FU16 Xr, Xi, Xn;
        #pragma unroll
        for (int p = 0; p < 4; ++p){
            int d0 = (quad << 3) + (p << 1);
            unsigned e0 = lds[d0*36 + cb2], e1 = lds[(d0+1)*36 + cb2];
            Xr.u[p] = codd ? ((e0 >> 16) | (e1 & 0xFFFF0000u)) : ((e0 & 0xFFFFu) | (e1 << 16));
            e0 = lds[32*36 + d0*36 + cb2]; e1 = lds[32*36 + (d0+1)*36 + cb2];
            Xi.u[p] = codd ? ((e0 >> 16) | (e1 & 0xFFFF0000u)) : ((e0 & 0xFFFFu) | (e1 << 16));
            Xn.u[p] = Xi.u[p] ^ 0x80008000u;
        }
        #pragma unroll
        for (int et = 0; et < 2; ++et){
            f32x4 ar = (f32x4){0,0,0,0}, ai = (f32x4){0,0,0,0};
            ar = __builtin_amdgcn_mfma_f32_16x16x32_f16(Ar[et].v, Xr.v, ar, 0, 0, 0);
            ar = __builtin_amdgcn_mfma_f32_16x16x32_f16(Ai[et].v, Xn.v, ar, 0, 0, 0);
            ai = __builtin_amdgcn_mfma_f32_16x16x32_f16(Ar[et].v, Xi.v, ai, 0, 0, 0);
            ai = __builtin_amdgcn_mfma_f32_16x16x32_f16(Ai[et].v, Xr.v, ai, 0, 0, 0);
            #pragma unroll
            for (int r = 0; r < 4; ++r){
                int e = (et << 4) + (quad << 2) + r;
                om[cbase2*2 + (size_t)e*NFFT + nb + colb] = packh(ar[r], ai[r]);
            }
        }
    }
}

// ---------- K5: fused 16384-pt inverse FFT + abs per row; fp16-packed complex in, f16 out (packed pairs) ----------
__global__ __launch_bounds__(1024, 8) void k_ifft_n(const unsigned* __restrict__ in, unsigned* __restrict__ outp){
    __shared__ unsigned sp[128*129];
    int lane = threadIdx.x & 63, wave = threadIdx.x >> 6;
    size_t rb = (size_t)blockIdx.x * NFFT;
    TwI tw; make_twi(tw);
    #pragma unroll 4
    for (int it = 0; it < 8; ++it){
        int jw = (wave << 3) + it;
        size_t base = rb + ((size_t)jw << 7);
        float a0, b0, a1, b1;
        unpackh(in[base + lane], a0, b0);
        unpackh(in[base + lane + 64], a1, b1);
        dit128t(tw, a0, b0, a1, b1);
        int kw = rev7(jw);
        float sn, cs;
        sincos_rev((float)(lane * kw) * 6.103515625e-05f, sn, cs);
        float r = a0*cs - b0*sn, i2 = a0*sn + b0*cs;
        sp[lane*129 + jw] = packh(r, i2);
        sincos_rev((float)((lane + 64) * kw) * 6.103515625e-05f, sn, cs);
        r = a1*cs - b1*sn; i2 = a1*sn + b1*cs;
        sp[(lane+64)*129 + jw] = packh(r, i2);
    }
    __syncthreads();
    float av0[8], av1[8];
    #pragma unroll
    for (int it = 0; it < 8; ++it){
        int pw = (wave << 3) + it;
        float a0, b0, a1, b1;
        unpackh(sp[pw*129 + lane],      a0, b0);
        unpackh(sp[pw*129 + lane + 64], a1, b1);
        dit128t(tw, a0, b0, a1, b1);
        av0[it] = sqrtf(a0*a0 + b0*b0);
        av1[it] = sqrtf(a1*a1 + b1*b1);
    }
    __syncthreads();
    // transpose via LDS at half width: u32 holds f16 pair of adjacent columns (pw, pw+1)
    #pragma unroll
    for (int p = 0; p < 4; ++p){
        sp[lane*65 + (wave << 2) + p]      = packh(av0[2*p], av0[2*p+1]);
        sp[(lane+64)*65 + (wave << 2) + p] = packh(av1[2*p], av1[2*p+1]);
    }
    __syncthreads();
    int row = threadIdx.x >> 3, cb = (threadIdx.x & 7) << 3;
    unsigned* ob = outp + ((size_t)blockIdx.x << 13) + row*64 + cb;
    const unsigned* s = &sp[row*65 + cb];
    *(uint4*)(ob)     = make_uint4(s[0], s[1], s[2], s[3]);
    *(uint4*)(ob + 4) = make_uint4(s[4], s[5], s[6], s[7]);
}

// ---------- K6: gating, IN-PLACE on fp16 half-planes ----------
__global__ __launch_bounds__(256) void k_gate(unsigned* spR, unsigned* spI,
                                              const float* __restrict__ w1, const float* __restrict__ b1,
                                              const float* __restrict__ bg, const float* __restrict__ bb_,
                                              const float* __restrict__ bm, const float* __restrict__ bv,
                                              const float* __restrict__ w2, const float* __restrict__ b2){
    __shared__ float w1T[256*17];
    __shared__ float w2s[256*16];
    __shared__ float yred[256*17];
    int t = threadIdx.x, g = t >> 6, col = t & 63;
    #pragma unroll
    for (int i = 0; i < 16; ++i) w1T[t*17 + i] = w1[i*256 + t];
    {
        const float4* s4 = (const float4*)w2; float4* d4 = (float4*)w2s;
        #pragma unroll
        for (int i = 0; i < 4; ++i) d4[i*256 + t] = s4[i*256 + t];
    }
    __syncthreads();
    int b = blockIdx.x >> 8;
    int n = ((blockIdx.x & 255) << 6) + col;
    int odd = n & 1;
    size_t base2 = (((size_t)b << 8) << 13) + (n >> 1);
    float y[16];
    #pragma unroll
    for (int r = 0; r < 16; ++r) y[r] = 0.f;
    for (int c = g << 6; c < (g << 6) + 64; ++c){
        float lo, hi; unpackh(spR[base2 + ((size_t)c << 13)], lo, hi);
        float xr = odd ? hi : lo;
        #pragma unroll
        for (int r = 0; r < 16; ++r) y[r] += w1T[c*17 + r] * xr;
    }
    #pragma unroll
    for (int r = 0; r < 16; ++r) yred[t*17 + r] = y[r];
    __syncthreads();
    #pragma unroll
    for (int r = 0; r < 16; ++r){
        float v = yred[col*17 + r] + yred[(col+64)*17 + r]
                + yred[(col+128)*17 + r] + yred[(col+192)*17 + r] + b1[r];
        v = (v - bm[r]) * rsqrtf(bv[r] + 1e-5f) * bg[r] + bb_[r];
        y[r] = fmaxf(v, 0.f);
    }
    for (int o = g << 6; o < (g << 6) + 64; ++o){
        float s = b2[o];
        #pragma unroll
        for (int r = 0; r < 16; ++r) s += w2s[o*16 + r] * y[r];
        float gg = 1.f / (1.f + __expf(-s)) * 6.103515625e-05f;   // sigmoid * 1/16384
        float ggN = __shfl_xor(gg, 1, 64);
        size_t mi = base2 + ((size_t)o << 13);
        if (!odd){
            float lo, hi; unpackh(spR[mi], lo, hi);
            spR[mi] = packh(gg*lo, ggN*hi);
        } else {
            float lo, hi; unpackh(spI[mi], lo, hi);
            spI[mi] = packh(ggN*lo, gg*hi);
        }
    }
}

// ---------- K7: fused ifft2 per image + abs -> f16 (packed pairs) into Cat1 ----------
__global__ __launch_bounds__(1024, 8) void k_ifft2_gate(const unsigned* __restrict__ spR,
                                                        const unsigned* __restrict__ spI,
                                                        unsigned* __restrict__ outp){
    __shared__ unsigned sp[128*129];
    int lane = threadIdx.x & 63, wave = threadIdx.x >> 6;
    TwI tw; make_twi(tw);
    size_t ib = (size_t)blockIdx.x * NFFT;
    #pragma unroll 4
    for (int it = 0; it < 8; ++it){
        int jw = (wave << 3) + it;
        size_t m = (ib + ((size_t)jw << 7)) >> 1;
        int k = lane >> 1; bool od = lane & 1;
        float lo, hi, a0, b0, a1, b1;
        unpackh(spR[m + k], lo, hi);      a0 = od ? hi : lo;
        unpackh(spI[m + k], lo, hi);      b0 = od ? hi : lo;
        unpackh(spR[m + 32 + k], lo, hi); a1 = od ? hi : lo;
        unpackh(spI[m + 32 + k], lo, hi); b1 = od ? hi : lo;
        dit128t(tw, a0, b0, a1, b1);
        sp[lane*129 + jw]      = packh(a0, b0);
        sp[(lane+64)*129 + jw] = packh(a1, b1);
    }
    __syncthreads();
    #pragma unroll 4
    for (int it = 0; it < 8; ++it){
        int ph = (wave << 3) + it;
        float a0, b0, a1, b1;
        unpackh(sp[ph*129 + lane],      a0, b0);
        unpackh(sp[ph*129 + lane + 64], a1, b1);
        dit128t(tw, a0, b0, a1, b1);
        float v0 = sqrtf(a0*a0 + b0*b0), v1 = sqrtf(a1*a1 + b1*b1);
        float p0 = __shfl_xor(v0, 1, 64), p1 = __shfl_xor(v1, 1, 64);
        if (!(lane & 1)){
            size_t o2 = ((size_t)blockIdx.x << 13) + (ph << 6);
            outp[o2 + (lane >> 1)]      = packh(v0, p0);
            outp[o2 + 32 + (lane >> 1)] = packh(v1, p1);
        }
    }
}

// ---------- K7b: pack pw into f16 pairs (along k) ----------
__global__ __launch_bounds__(256) void k_pw_cvt(const float* __restrict__ pw, unsigned* __restrict__ pwp){
    int i = (blockIdx.x << 10) + (threadIdx.x << 2);
    float4 v = *(const float4*)(pw + i);
    uint2 o;
    o.x = packh(v.x, v.y); o.y = packh(v.z, v.w);
    *(uint2*)(pwp + (i >> 1)) = o;
}

// ---------- K8: projection via f16 MFMA, single product per fragment ----------
__global__ __launch_bounds__(256) void k_proj(const unsigned* __restrict__ cat0, const unsigned* __restrict__ cat1,
                                              const unsigned* __restrict__ pwp, float* __restrict__ out){
    __shared__ unsigned As[128*17];   // [o][k2] f16 pairs along k, stride 17
    __shared__ unsigned Bs[32*65];    // [k][n2] f16 pairs along n, stride 65
    int t = threadIdx.x, lane = t & 63, wave = t >> 6;
    int quad = lane >> 4, l15 = lane & 15;
    int b  = blockIdx.x >> 8;
    int mo = (blockIdx.x >> 7) & 1;
    int nt = blockIdx.x & 127;
    int n0 = nt << 7;
    int n0_2 = nt << 6;
    int wr = (wave >> 1) << 6;
    int wc = (wave & 1) << 6;

    f32x4 acc[4][4];
    #pragma unroll
    for (int i = 0; i < 4; ++i)
        #pragma unroll
        for (int j = 0; j < 4; ++j) acc[i][j] = (f32x4){0.f,0.f,0.f,0.f};

    int ao = t >> 1, ak = (t & 1) << 3;
    int bk = t >> 3, bn8 = (t & 7) << 3;
    int par = l15 & 1;

    for (int ks = 0; ks < 16; ++ks){
        __syncthreads();
        {
            const unsigned* ap = pwp + (size_t)((mo << 7) + ao)*256 + (ks << 4) + ak;
            #pragma unroll
            for (int i = 0; i < 8; ++i) As[ao*17 + ak + i] = ap[i];
        }
        {
            int q = (ks << 5) + bk;
            const unsigned* srow = (q < 256) ? (cat0 + (size_t)((b << 8) + q) * 8192)
                                             : (cat1 + (size_t)((b << 8) + q - 256) * 8192);
            const unsigned* sp_ = srow + n0_2 + bn8;
            *(uint4*)&Bs[bk*65 + bn8]     = *(const uint4*)sp_;
            *(uint4*)&Bs[bk*65 + bn8 + 4] = *(const uint4*)(sp_ + 4);
        }
        __syncthreads();
        FU16 Af[4], Bf[4];
        #pragma unroll
        for (int mi = 0; mi < 4; ++mi){
            const unsigned* ap = &As[(wr + (mi << 4) + l15)*17 + (quad << 2)];
            #pragma unroll
            for (int p = 0; p < 4; ++p) Af[mi].u[p] = ap[p];
        }
        #pragma unroll
        for (int ni = 0; ni < 4; ++ni){
            int n2 = (wc + (ni << 4) + l15) >> 1;
            #pragma unroll
            for (int p = 0; p < 4; ++p){
                unsigned e0 = Bs[((quad << 3) + 2*p)*65 + n2];
                unsigned e1 = Bs[((quad << 3) + 2*p + 1)*65 + n2];
                Bf[ni].u[p] = par ? ((e0 >> 16) | (e1 & 0xFFFF0000u))
                                  : ((e0 & 0xFFFFu) | (e1 << 16));
            }
        }
        #pragma unroll
        for (int mi = 0; mi < 4; ++mi)
            #pragma unroll
            for (int ni = 0; ni < 4; ++ni)
                acc[mi][ni] = __builtin_amdgcn_mfma_f32_16x16x32_f16(Af[mi].v, Bf[ni].v, acc[mi][ni], 0, 0, 0);
    }
    size_t obase = (size_t)((b << 8) + (mo << 7));
    #pragma unroll
    for (int mi = 0; mi < 4; ++mi)
        #pragma unroll
        for (int ni = 0; ni < 4; ++ni){
            int o_ = wr + (mi << 4) + (quad << 2);
            int n_ = n0 + wc + (ni << 4) + l15;
            float* op = out + (obase + o_)*NFFT + n_;
            #pragma unroll
            for (int r = 0; r < 4; ++r) op[(size_t)r*NFFT] = acc[mi][ni][r];
        }
}

// ---------- host ----------
extern "C" void kernel_launch(void* const* d_in, const int* in_sizes, int n_in,
                              void* d_out, int out_size, void* d_ws, size_t ws_size,
                              hipStream_t stream) {
    const float* x    = (const float*)d_in[0];
    const float* temp = (const float*)d_in[1];
    const float* w1   = (const float*)d_in[2];
    const float* b1   = (const float*)d_in[3];
    const float* bg   = (const float*)d_in[4];
    const float* bb_  = (const float*)d_in[5];
    const float* bm   = (const float*)d_in[6];
    const float* bv   = (const float*)d_in[7];
    const float* w2   = (const float*)d_in[8];
    const float* b2   = (const float*)d_in[9];
    const float* pw   = (const float*)d_in[10];
    float* out = (float*)d_out;

    float* ws = (float*)d_ws;
    unsigned* SpecR = (unsigned*)ws;             // fp16 re half-plane, NP/2 u32
    unsigned* SpecI = SpecR + (NP >> 1);         // fp16 im half-plane
    unsigned* Ecat  = (unsigned*)(ws + NP);      // Gpart scratch -> mix out (fp16 cplx), read by ifft_n
    unsigned* Cat0  = (unsigned*)(ws + 2*NP);    // ifft_n out, f16 pairs (8.4M u32)
    unsigned* Cat1  = Cat0 + 8388608;            // ifft2_gate out, f16 pairs (8.4M u32)
    float* norm2 = ws + 3*NP;                    // 1024
    float* G     = norm2 + 1024;                 // 65536
    float* attn2 = G + 65536;                    // 65536
    unsigned* pwpack = (unsigned*)(attn2 + 65536);  // 65536 u32 (f16 pairs)
    float* Gpart = (float*)Ecat;                 // 8 MB scratch, dead until k_mix

    size_t need = (3*NP + 1024 + 65536 + 65536 + 131072) * sizeof(float);
    if (ws_size < need) return;

    k_pw_cvt<<<128, 256, 0, stream>>>(pw, pwpack);
    k_fft2_fwd<<<1024, 1024, 0, stream>>>(x, SpecR, SpecI, norm2);
    k_gram<<<1024, 256, 0, stream>>>(SpecR, SpecI, Gpart);
    k_gram_red<<<256, 256, 0, stream>>>(Gpart, G);
    k_attn<<<32, 256, 0, stream>>>(G, norm2, temp, attn2);
    k_mix<<<1024, 256, 0, stream>>>(SpecR, SpecI, attn2, Ecat);
    k_ifft_n<<<1024, 1024, 0, stream>>>(Ecat, Cat0);
    k_gate<<<1024, 256, 0, stream>>>(SpecR, SpecI, w1, b1, bg, bb_, bm, bv, w2, b2);
    k_ifft2_gate<<<1024, 1024, 0, stream>>>(SpecR, SpecI, Cat1);
    k_proj<<<1024, 256, 0, stream>>>(Cat0, Cat1, pwpack, out);
    (void)in_sizes; (void)n_in; (void)out_size; (void)ws_size;
}

// Round 9
// 450.919 us; speedup vs baseline: 1.4274x; 1.4274x over previous
//
#include <hip/hip_runtime.h>
#include <math.h>

// Problem constants: b=4, c=256, heads=8, c/head=32, h=w=128, n=16384, cr=16
#define NFFT 16384
static constexpr size_t NP = 16777216; // one fp32 plane = 1024 * 16384 floats

typedef short bf16x8 __attribute__((ext_vector_type(8)));
typedef __fp16 f16x8 __attribute__((ext_vector_type(8)));
typedef float f32x4  __attribute__((ext_vector_type(4)));
typedef __fp16 h16x2 __attribute__((ext_vector_type(2)));

union FU  { bf16x8 v; unsigned u[4]; };
union FU16{ f16x8  v; unsigned u[4]; };

// ---------- fast cross-lane xor shuffles ----------
// xor1/xor2: DPP quad_perm (VALU-rate, no lgkmcnt). xor4/8/16: ds_swizzle BitMode.
// xor32: generic shfl (ds_bpermute). All exact, all 64 lanes active.
__device__ __forceinline__ float shfx1(float x){
    return __int_as_float(__builtin_amdgcn_mov_dpp(__float_as_int(x), 0xB1, 0xF, 0xF, true));
}
__device__ __forceinline__ float shfx2(float x){
    return __int_as_float(__builtin_amdgcn_mov_dpp(__float_as_int(x), 0x4E, 0xF, 0xF, true));
}
__device__ __forceinline__ float shfx(float x, int m){
    if (m == 1)  return shfx1(x);
    if (m == 2)  return shfx2(x);
    if (m == 4)  return __int_as_float(__builtin_amdgcn_ds_swizzle(__float_as_int(x), 0x101F));
    if (m == 8)  return __int_as_float(__builtin_amdgcn_ds_swizzle(__float_as_int(x), 0x201F));
    if (m == 16) return __int_as_float(__builtin_amdgcn_ds_swizzle(__float_as_int(x), 0x401F));
    return __shfl_xor(x, m, 64);
}

// ---------- helpers ----------
__device__ __forceinline__ void sincos_rev(float rv, float& sn, float& cs){
    sn = __builtin_amdgcn_sinf(rv);   // sin(2*pi*rv)
    cs = __builtin_amdgcn_cosf(rv);
}
__device__ __forceinline__ int rev7(int v){ return (int)(__brev((unsigned)v) >> 25); }

__device__ __forceinline__ unsigned f2bf(float f){
    unsigned u = __float_as_uint(f);
    return (u + 0x7FFFu + ((u >> 16) & 1u)) >> 16;   // round-to-nearest-even
}
__device__ __forceinline__ float bf2f(unsigned h){ return __uint_as_float(h << 16); }

// fp16x2 pack/unpack: packh(a,b) -> (a in LOW 16, b in HIGH 16)
union HU2 { h16x2 h; unsigned u; };
__device__ __forceinline__ unsigned packh(float a, float b){
    HU2 z; z.h = __builtin_amdgcn_cvt_pkrtz(a, b); return z.u;
}
__device__ __forceinline__ void unpackh(unsigned u, float& a, float& b){
    HU2 z; z.u = u; a = (float)z.h.x; b = (float)z.h.y;
}

// ---------- sign/identity-folded per-lane twiddles ----------
struct TwF { float cw[6], sw[6], sg[6], c6, s6; };
__device__ __forceinline__ void make_twf(TwF& t){
    const int l = threadIdx.x & 63;
    #pragma unroll
    for (int lg = 0; lg < 6; ++lg){
        int m = 1 << lg;
        bool up = (l & m) != 0;
        int e = (l & (m-1)) * (64 >> lg);
        float sn, cs; sincos_rev((float)e * 0.0078125f, sn, cs);
        t.cw[lg] = up ? cs : 1.f;
        t.sw[lg] = up ? -sn : 0.f;
        t.sg[lg] = up ? -1.f : 1.f;
    }
    sincos_rev((float)l * 0.0078125f, t.s6, t.c6);
}
// DIT (inverse), select-free: every lane multiplies SELF by folded w
// (up lane: w = e^{+2pi i e/128}, down lane: 1), shuffles the product, then
// y = shfl(q) + sg*q.
struct TwI { float cw[6], sw[6], sg[6], c6, s6; };
__device__ __forceinline__ void make_twi(TwI& t){
    const int l = threadIdx.x & 63;
    #pragma unroll
    for (int lg = 0; lg < 6; ++lg){
        int m = 1 << lg;
        bool up = (l & m) != 0;
        int e = (l & (m-1)) * (64 >> lg);
        float sn, cs; sincos_rev((float)e * 0.0078125f, sn, cs);
        t.cw[lg] = up ? cs : 1.f;
        t.sw[lg] = up ? sn : 0.f;
        t.sg[lg] = up ? -1.f : 1.f;
    }
    sincos_rev((float)l * 0.0078125f, t.s6, t.c6);
}

// DIF forward: natural in, slot j holds X[rev7(j)] out. W = e^{-2pi i/128}
__device__ __forceinline__ void dif128t(const TwF& t, float& r0, float& i0, float& r1, float& i1){
    {
        float ar = r0 + r1, ai = i0 + i1;
        float br = r0 - r1, bi = i0 - i1;
        r0 = ar; i0 = ai;
        r1 =  br*t.c6 + bi*t.s6;
        i1 = -br*t.s6 + bi*t.c6;
    }
    #pragma unroll
    for (int lg = 5; lg >= 0; --lg){
        int m = 1 << lg;
        float cw = t.cw[lg], sw = t.sw[lg], sg = t.sg[lg];
        float pr = shfx(r0, m), pi = shfx(i0, m);
        float tr = fmaf(sg, r0, pr), ti = fmaf(sg, i0, pi);
        r0 = tr*cw - ti*sw;
        i0 = tr*sw + ti*cw;
        pr = shfx(r1, m); pi = shfx(i1, m);
        tr = fmaf(sg, r1, pr); ti = fmaf(sg, i1, pi);
        r1 = tr*cw - ti*sw;
        i1 = tr*sw + ti*cw;
    }
}

// DIT inverse (unnormalized): slot j holds X[rev7(j)] in, natural out. W = e^{+2pi i/128}
__device__ __forceinline__ void dit128t(const TwI& t, float& r0, float& i0, float& r1, float& i1){
    #pragma unroll
    for (int lg = 0; lg <= 5; ++lg){
        int m = 1 << lg;
        float cw = t.cw[lg], sw = t.sw[lg], sg = t.sg[lg];
        float qr = r0*cw - i0*sw, qi = r0*sw + i0*cw;
        float pr = shfx(qr, m), pi = shfx(qi, m);
        r0 = fmaf(sg, qr, pr);
        i0 = fmaf(sg, qi, pi);
        qr = r1*cw - i1*sw; qi = r1*sw + i1*cw;
        pr = shfx(qr, m); pi = shfx(qi, m);
        r1 = fmaf(sg, qr, pr);
        i1 = fmaf(sg, qi, pi);
    }
    {
        float wr = r1*t.c6 - i1*t.s6, wi = r1*t.s6 + i1*t.c6;
        float ar = r0 + wr, ai = i0 + wi;
        r1 = r0 - wr; i1 = i0 - wi;
        r0 = ar; i0 = ai;
    }
}

// ---------- K1: fused forward fft2 per image -> fp16 half-planes SpecR/SpecI ----------
__global__ __launch_bounds__(1024, 8) void k_fft2_fwd(const float* __restrict__ x,
                                                   unsigned* __restrict__ spR, unsigned* __restrict__ spI,
                                                   float* __restrict__ norm2){
    __shared__ unsigned sp[128*129];
    __shared__ float red[16];
    int lane = threadIdx.x & 63, wave = threadIdx.x >> 6;
    int img = blockIdx.x;
    TwF tw; make_twf(tw);
    const float* base = x + (size_t)img * NFFT;
    #pragma unroll 2
    for (int it = 0; it < 8; ++it){
        int h = (wave << 3) + it;
        float a0 = base[h*128 + lane], b0 = 0.f;
        float a1 = base[h*128 + lane + 64], b1 = 0.f;
        dif128t(tw, a0, b0, a1, b1);
        sp[lane*129 + h]      = packh(a0, b0);
        sp[(lane+64)*129 + h] = packh(a1, b1);
    }
    __syncthreads();
    float acc0 = 0.f, acc1 = 0.f;
    #pragma unroll 2
    for (int it = 0; it < 8; ++it){
        int j = (wave << 3) + it;
        float a0, b0, a1, b1;
        unpackh(sp[j*129 + lane],      a0, b0);
        unpackh(sp[j*129 + lane + 64], a1, b1);
        dif128t(tw, a0, b0, a1, b1);
        acc0 += a0*a0 + b0*b0;
        acc1 += a1*a1 + b1*b1;
        float t0 = shfx1(a0), u0 = shfx1(b0);
        float t1 = shfx1(a1), u1 = shfx1(b1);
        size_t m = (size_t)img*8192 + (size_t)j*64;
        int k = lane >> 1;
        if (!(lane & 1)){
            spR[m + k]      = packh(a0, t0);
            spR[m + 32 + k] = packh(a1, t1);
        } else {
            spI[m + k]      = packh(u0, b0);
            spI[m + 32 + k] = packh(u1, b1);
        }
    }
    float acc = acc0 + acc1;
    #pragma unroll
    for (int m = 32; m >= 1; m >>= 1) acc += shfx(acc, m);
    if (lane == 0) red[wave] = acc;
    __syncthreads();
    if (threadIdx.x == 0){
        float s = 0.f;
        #pragma unroll
        for (int i = 0; i < 16; ++i) s += red[i];
        norm2[img] = s;
    }
}

// ---------- K2: gram via f16 MFMA, zero-conversion staging ----------
__global__ __launch_bounds__(256) void k_gram(const unsigned* __restrict__ spR, const unsigned* __restrict__ spI,
                                              float* __restrict__ Gpart){
    __shared__ unsigned lds[2*32*132];
    int t = threadIdx.x, lane = t & 63, wave = t >> 6;
    int bh = blockIdx.x >> 5;
    int ks = blockIdx.x & 31;          // 32 k-splits, K=512 each
    size_t cbase2 = (size_t)bh * 32 * 8192;
    int k0blk = ks << 9;

    int sc = t >> 3, tk = t & 7;

    f32x4 aRe[2][2], aIm[2][2];
    #pragma unroll
    for (int i = 0; i < 2; ++i)
        #pragma unroll
        for (int j = 0; j < 2; ++j){ aRe[i][j] = (f32x4){0,0,0,0}; aIm[i][j] = (f32x4){0,0,0,0}; }

    for (int tile = 0; tile < 2; ++tile){
        int kb = k0blk + (tile << 8);
        __syncthreads();
        {
            const unsigned* pr  = spR + cbase2 + (size_t)sc*8192 + (kb >> 1) + tk*16;
            const unsigned* pi_ = spI + cbase2 + (size_t)sc*8192 + (kb >> 1) + tk*16;
            unsigned* dr = &lds[sc*132 + tk*16];
            unsigned* di = &lds[32*132 + sc*132 + tk*16];
            #pragma unroll
            for (int j = 0; j < 4; ++j){
                *(uint4*)(dr + 4*j) = *(const uint4*)(pr + 4*j);
                *(uint4*)(di + 4*j) = *(const uint4*)(pi_ + 4*j);
            }
        }
        __syncthreads();
        #pragma unroll
        for (int ss = 0; ss < 2; ++ss){
            int s = wave + (ss << 2);
            int kbase = (s << 4) + ((lane >> 4) << 2);
            FU16 fr0, fr1, fi0, fi1, fn0, fn1;
            *(uint4*)fr0.u = *(const uint4*)&lds[ (lane & 15)*132 + kbase ];
            *(uint4*)fr1.u = *(const uint4*)&lds[ ((lane & 15) + 16)*132 + kbase ];
            *(uint4*)fi0.u = *(const uint4*)&lds[ 32*132 + (lane & 15)*132 + kbase ];
            *(uint4*)fi1.u = *(const uint4*)&lds[ 32*132 + ((lane & 15) + 16)*132 + kbase ];
            #pragma unroll
            for (int p = 0; p < 4; ++p){ fn0.u[p] = fi0.u[p] ^ 0x80008000u; fn1.u[p] = fi1.u[p] ^ 0x80008000u; }
            aRe[0][0] = __builtin_amdgcn_mfma_f32_16x16x32_f16(fr0.v, fr0.v, aRe[0][0], 0, 0, 0);
            aRe[0][0] = __builtin_amdgcn_mfma_f32_16x16x32_f16(fn0.v, fi0.v, aRe[0][0], 0, 0, 0);
            aRe[0][1] = __builtin_amdgcn_mfma_f32_16x16x32_f16(fr0.v, fr1.v, aRe[0][1], 0, 0, 0);
            aRe[0][1] = __builtin_amdgcn_mfma_f32_16x16x32_f16(fn0.v, fi1.v, aRe[0][1], 0, 0, 0);
            aRe[1][0] = __builtin_amdgcn_mfma_f32_16x16x32_f16(fr1.v, fr0.v, aRe[1][0], 0, 0, 0);
            aRe[1][0] = __builtin_amdgcn_mfma_f32_16x16x32_f16(fn1.v, fi0.v, aRe[1][0], 0, 0, 0);
            aRe[1][1] = __builtin_amdgcn_mfma_f32_16x16x32_f16(fr1.v, fr1.v, aRe[1][1], 0, 0, 0);
            aRe[1][1] = __builtin_amdgcn_mfma_f32_16x16x32_f16(fn1.v, fi1.v, aRe[1][1], 0, 0, 0);
            aIm[0][0] = __builtin_amdgcn_mfma_f32_16x16x32_f16(fr0.v, fi0.v, aIm[0][0], 0, 0, 0);
            aIm[0][0] = __builtin_amdgcn_mfma_f32_16x16x32_f16(fi0.v, fr0.v, aIm[0][0], 0, 0, 0);
            aIm[0][1] = __builtin_amdgcn_mfma_f32_16x16x32_f16(fr0.v, fi1.v, aIm[0][1], 0, 0, 0);
            aIm[0][1] = __builtin_amdgcn_mfma_f32_16x16x32_f16(fi0.v, fr1.v, aIm[0][1], 0, 0, 0);
            aIm[1][0] = __builtin_amdgcn_mfma_f32_16x16x32_f16(fr1.v, fi0.v, aIm[1][0], 0, 0, 0);
            aIm[1][0] = __builtin_amdgcn_mfma_f32_16x16x32_f16(fi1.v, fr0.v, aIm[1][0], 0, 0, 0);
            aIm[1][1] = __builtin_amdgcn_mfma_f32_16x16x32_f16(fr1.v, fi1.v, aIm[1][1], 0, 0, 0);
            aIm[1][1] = __builtin_amdgcn_mfma_f32_16x16x32_f16(fi1.v, fr1.v, aIm[1][1], 0, 0, 0);
        }
    }
    __syncthreads();
    float* rbuf = (float*)lds;
    int dcol = lane & 15, rrow = lane >> 4;
    #pragma unroll
    for (int i = 0; i < 2; ++i)
        #pragma unroll
        for (int j = 0; j < 2; ++j)
            #pragma unroll
            for (int r = 0; r < 4; ++r){
                int c = (i << 4) + (rrow << 2) + r;
                int d = (j << 4) + dcol;
                rbuf[wave*2048 + ((c << 5) + d)*2    ] = aRe[i][j][r];
                rbuf[wave*2048 + ((c << 5) + d)*2 + 1] = aIm[i][j][r];
            }
    __syncthreads();
    float* gp = Gpart + (size_t)blockIdx.x * 2048;
    for (int idx = t; idx < 2048; idx += 256)
        gp[idx] = rbuf[idx] + rbuf[2048 + idx] + rbuf[4096 + idx] + rbuf[6144 + idx];
}

// ---------- K2b: reduce 32 k-split partials per bh ----------
__global__ __launch_bounds__(256) void k_gram_red(const float* __restrict__ Gpart, float* __restrict__ G){
    int bh = blockIdx.x >> 3;
    int q  = ((blockIdx.x & 7) << 8) + threadIdx.x;
    const float* gp = Gpart + (size_t)bh * 32 * 2048 + q;
    float s = 0.f;
    #pragma unroll 8
    for (int p = 0; p < 32; ++p) s += gp[(size_t)p * 2048];
    G[(size_t)bh * 2048 + q] = s;
}

// ---------- K3: normalize, temperature, complex softmax, fold IF32 * (1/524288) ----------
__global__ __launch_bounds__(256) void k_attn(const float* __restrict__ G, const float* __restrict__ norm2,
                                              const float* __restrict__ temp, float* __restrict__ attn2){
    __shared__ float ar[32*33], ai[32*33];
    int bh = blockIdx.x, h = bh & 7, t = threadIdx.x;
    if (t < 32){
        float tv = temp[h];
        float nc = fmaxf(sqrtf(norm2[(bh<<5) + t]), 1e-12f);
        const float* gr = G + (size_t)bh*2048 + t*64;
        float mr = -1e30f, mi = -1e30f;
        for (int d = 0; d < 32; ++d){
            float nd = fmaxf(sqrtf(norm2[(bh<<5) + d]), 1e-12f);
            float s = tv / (nc * nd);
            float vr = gr[d*2] * s, vi = gr[d*2+1] * s;
            ar[t*33+d] = vr; ai[t*33+d] = vi;
            mr = fmaxf(mr, vr); mi = fmaxf(mi, vi);
        }
        float sr = 0.f, si = 0.f;
        for (int d = 0; d < 32; ++d){
            float er = __expf(ar[t*33+d] - mr), ei = __expf(ai[t*33+d] - mi);
            ar[t*33+d] = er; ai[t*33+d] = ei; sr += er; si += ei;
        }
        sr = 1.f/sr; si = 1.f/si;
        for (int d = 0; d < 32; ++d){ ar[t*33+d] *= sr; ai[t*33+d] *= si; }
    }
    __syncthreads();
    const float S = 1.f / 524288.f;
    for (int q = t; q < 1024; q += 256){
        int e = q >> 5, d = q & 31;
        float sr = 0.f, si = 0.f;
        for (int c = 0; c < 32; ++c){
            float sn, cs; sincos_rev((float)((e*c) & 31) * 0.03125f, sn, cs);
            float xr = ar[c*33+d], xi = ai[c*33+d];
            sr += cs*xr - sn*xi;
            si += cs*xi + sn*xr;
        }
        attn2[(size_t)bh*2048 + q*2]     = sr * S;
        attn2[(size_t)bh*2048 + q*2 + 1] = si * S;
    }
}

// ---------- K4: mix[e][n] = sum_d attn2[e][d] * X[d][n] via f16 MFMA ----------
__global__ __launch_bounds__(256) void k_mix(const unsigned* __restrict__ spR, const unsigned* __restrict__ spI,
                                             const float* __restrict__ attn2,
                                             unsigned* __restrict__ om){
    __shared__ unsigned lds[2*32*36];
    __shared__ float a2s[2048];
    int t = threadIdx.x, lane = t & 63, wave = t >> 6;
    int quad = lane >> 4, l15 = lane & 15;
    int bh = blockIdx.x >> 5;
    int n0 = (blockIdx.x & 31) << 9;
    size_t cbase2 = (size_t)bh * 32 * 8192;
    {
        const float4* s4 = (const float4*)(attn2 + (size_t)bh*2048);
        float4* d4 = (float4*)a2s;
        d4[t] = s4[t]; d4[t + 256] = s4[t + 256];
    }
    __syncthreads();
    FU16 Ar[2], Ai[2];
    #pragma unroll
    for (int et = 0; et < 2; ++et){
        int e = (et << 4) + l15;
        #pragma unroll
        for (int p = 0; p < 4; ++p){
            int d0 = (quad << 3) + (p << 1);
            Ar[et].u[p] = packh(a2s[(e*32 + d0)*2],     a2s[(e*32 + d0 + 1)*2]);
            Ai[et].u[p] = packh(a2s[(e*32 + d0)*2 + 1], a2s[(e*32 + d0 + 1)*2 + 1]);
        }
    }
    int sd = t >> 3, sc4 = (t & 7) << 2;
    for (int tile = 0; tile < 8; ++tile){
        int nb = n0 + (tile << 6);
        __syncthreads();
        {
            size_t g2 = cbase2 + (size_t)sd*8192 + (nb >> 1) + sc4;
            *(uint4*)&lds[sd*36 + sc4]         = *(const uint4*)&spR[g2];
            *(uint4*)&lds[32*36 + sd*36 + sc4] = *(const uint4*)&spI[g2];
        }
        __syncthreads();
        int colb = (wave << 4) + l15;
        int cb2 = colb >> 1; bool codd = colb & 1;
        FU16 Xr, Xi, Xn;
        #pragma unroll
        for (int p = 0; p < 4; ++p){
            int d0 = (quad << 3) + (p << 1);
            unsigned e0 = lds[d0*36 + cb2], e1 = lds[(d0+1)*36 + cb2];
            Xr.u[p] = codd ? ((e0 >> 16) | (e1 & 0xFFFF0000u)) : ((e0 & 0xFFFFu) | (e1 << 16));
            e0 = lds[32*36 + d0*36 + cb2]; e1 = lds[32*36 + (d0+1)*36 + cb2];
            Xi.u[p] = codd ? ((e0 >> 16) | (e1 & 0xFFFF0000u)) : ((e0 & 0xFFFFu) | (e1 << 16));
            Xn.u[p] = Xi.u[p] ^ 0x80008000u;
        }
        #pragma unroll
        for (int et = 0; et < 2; ++et){
            f32x4 ar = (f32x4){0,0,0,0}, ai = (f32x4){0,0,0,0};
            ar = __builtin_amdgcn_mfma_f32_16x16x32_f16(Ar[et].v, Xr.v, ar, 0, 0, 0);
            ar = __builtin_amdgcn_mfma_f32_16x16x32_f16(Ai[et].v, Xn.v, ar, 0, 0, 0);
            ai = __builtin_amdgcn_mfma_f32_16x16x32_f16(Ar[et].v, Xi.v, ai, 0, 0, 0);
            ai = __builtin_amdgcn_mfma_f32_16x16x32_f16(Ai[et].v, Xr.v, ai, 0, 0, 0);
            #pragma unroll
            for (int r = 0; r < 4; ++r){
                int e = (et << 4) + (quad << 2) + r;
                om[cbase2*2 + (size_t)e*NFFT + nb + colb] = packh(ar[r], ai[r]);
            }
        }
    }
}

// ---------- K5: fused 16384-pt inverse FFT + abs per row; fp16-packed complex in, f16 out (packed pairs) ----------
__global__ __launch_bounds__(1024, 8) void k_ifft_n(const unsigned* __restrict__ in, unsigned* __restrict__ outp){
    __shared__ unsigned sp[128*129];
    int lane = threadIdx.x & 63, wave = threadIdx.x >> 6;
    size_t rb = (size_t)blockIdx.x * NFFT;
    TwI tw; make_twi(tw);
    #pragma unroll 2
    for (int it = 0; it < 8; ++it){
        int jw = (wave << 3) + it;
        size_t base = rb + ((size_t)jw << 7);
        float a0, b0, a1, b1;
        unpackh(in[base + lane], a0, b0);
        unpackh(in[base + lane + 64], a1, b1);
        dit128t(tw, a0, b0, a1, b1);
        int kw = rev7(jw);
        float sn, cs;
        sincos_rev((float)(lane * kw) * 6.103515625e-05f, sn, cs);
        float r = a0*cs - b0*sn, i2 = a0*sn + b0*cs;
        sp[lane*129 + jw] = packh(r, i2);
        sincos_rev((float)((lane + 64) * kw) * 6.103515625e-05f, sn, cs);
        r = a1*cs - b1*sn; i2 = a1*sn + b1*cs;
        sp[(lane+64)*129 + jw] = packh(r, i2);
    }
    __syncthreads();
    float av0[8], av1[8];
    #pragma unroll
    for (int it = 0; it < 8; ++it){
        int pw = (wave << 3) + it;
        float a0, b0, a1, b1;
        unpackh(sp[pw*129 + lane],      a0, b0);
        unpackh(sp[pw*129 + lane + 64], a1, b1);
        dit128t(tw, a0, b0, a1, b1);
        av0[it] = sqrtf(a0*a0 + b0*b0);
        av1[it] = sqrtf(a1*a1 + b1*b1);
    }
    __syncthreads();
    // transpose via LDS at half width: u32 holds f16 pair of adjacent columns (pw, pw+1)
    #pragma unroll
    for (int p = 0; p < 4; ++p){
        sp[lane*65 + (wave << 2) + p]      = packh(av0[2*p], av0[2*p+1]);
        sp[(lane+64)*65 + (wave << 2) + p] = packh(av1[2*p], av1[2*p+1]);
    }
    __syncthreads();
    int row = threadIdx.x >> 3, cb = (threadIdx.x & 7) << 3;
    unsigned* ob = outp + ((size_t)blockIdx.x << 13) + row*64 + cb;
    const unsigned* s = &sp[row*65 + cb];
    *(uint4*)(ob)     = make_uint4(s[0], s[1], s[2], s[3]);
    *(uint4*)(ob + 4) = make_uint4(s[4], s[5], s[6], s[7]);
}

// ---------- K6: gating, IN-PLACE on fp16 half-planes ----------
__global__ __launch_bounds__(256) void k_gate(unsigned* spR, unsigned* spI,
                                              const float* __restrict__ w1, const float* __restrict__ b1,
                                              const float* __restrict__ bg, const float* __restrict__ bb_,
                                              const float* __restrict__ bm, const float* __restrict__ bv,
                                              const float* __restrict__ w2, const float* __restrict__ b2){
    __shared__ float w1T[256*17];
    __shared__ float w2s[256*16];
    __shared__ float yred[256*17];
    int t = threadIdx.x, g = t >> 6, col = t & 63;
    #pragma unroll
    for (int i = 0; i < 16; ++i) w1T[t*17 + i] = w1[i*256 + t];
    {
        const float4* s4 = (const float4*)w2; float4* d4 = (float4*)w2s;
        #pragma unroll
        for (int i = 0; i < 4; ++i) d4[i*256 + t] = s4[i*256 + t];
    }
    __syncthreads();
    int b = blockIdx.x >> 8;
    int n = ((blockIdx.x & 255) << 6) + col;
    int odd = n & 1;
    size_t base2 = (((size_t)b << 8) << 13) + (n >> 1);
    float y[16];
    #pragma unroll
    for (int r = 0; r < 16; ++r) y[r] = 0.f;
    for (int c = g << 6; c < (g << 6) + 64; ++c){
        float lo, hi; unpackh(spR[base2 + ((size_t)c << 13)], lo, hi);
        float xr = odd ? hi : lo;
        #pragma unroll
        for (int r = 0; r < 16; ++r) y[r] += w1T[c*17 + r] * xr;
    }
    #pragma unroll
    for (int r = 0; r < 16; ++r) yred[t*17 + r] = y[r];
    __syncthreads();
    #pragma unroll
    for (int r = 0; r < 16; ++r){
        float v = yred[col*17 + r] + yred[(col+64)*17 + r]
                + yred[(col+128)*17 + r] + yred[(col+192)*17 + r] + b1[r];
        v = (v - bm[r]) * rsqrtf(bv[r] + 1e-5f) * bg[r] + bb_[r];
        y[r] = fmaxf(v, 0.f);
    }
    for (int o = g << 6; o < (g << 6) + 64; ++o){
        float s = b2[o];
        #pragma unroll
        for (int r = 0; r < 16; ++r) s += w2s[o*16 + r] * y[r];
        float gg = 1.f / (1.f + __expf(-s)) * 6.103515625e-05f;   // sigmoid * 1/16384
        float ggN = shfx1(gg);
        size_t mi = base2 + ((size_t)o << 13);
        if (!odd){
            float lo, hi; unpackh(spR[mi], lo, hi);
            spR[mi] = packh(gg*lo, ggN*hi);
        } else {
            float lo, hi; unpackh(spI[mi], lo, hi);
            spI[mi] = packh(ggN*lo, gg*hi);
        }
    }
}

// ---------- K7: fused ifft2 per image + abs -> f16 (packed pairs) into Cat1 ----------
__global__ __launch_bounds__(1024, 8) void k_ifft2_gate(const unsigned* __restrict__ spR,
                                                        const unsigned* __restrict__ spI,
                                                        unsigned* __restrict__ outp){
    __shared__ unsigned sp[128*129];
    int lane = threadIdx.x & 63, wave = threadIdx.x >> 6;
    TwI tw; make_twi(tw);
    size_t ib = (size_t)blockIdx.x * NFFT;
    #pragma unroll 2
    for (int it = 0; it < 8; ++it){
        int jw = (wave << 3) + it;
        size_t m = (ib + ((size_t)jw << 7)) >> 1;
        int k = lane >> 1; bool od = lane & 1;
        float lo, hi, a0, b0, a1, b1;
        unpackh(spR[m + k], lo, hi);      a0 = od ? hi : lo;
        unpackh(spI[m + k], lo, hi);      b0 = od ? hi : lo;
        unpackh(spR[m + 32 + k], lo, hi); a1 = od ? hi : lo;
        unpackh(spI[m + 32 + k], lo, hi); b1 = od ? hi : lo;
        dit128t(tw, a0, b0, a1, b1);
        sp[lane*129 + jw]      = packh(a0, b0);
        sp[(lane+64)*129 + jw] = packh(a1, b1);
    }
    __syncthreads();
    #pragma unroll 2
    for (int it = 0; it < 8; ++it){
        int ph = (wave << 3) + it;
        float a0, b0, a1, b1;
        unpackh(sp[ph*129 + lane],      a0, b0);
        unpackh(sp[ph*129 + lane + 64], a1, b1);
        dit128t(tw, a0, b0, a1, b1);
        float v0 = sqrtf(a0*a0 + b0*b0), v1 = sqrtf(a1*a1 + b1*b1);
        float p0 = shfx1(v0), p1 = shfx1(v1);
        if (!(lane & 1)){
            size_t o2 = ((size_t)blockIdx.x << 13) + (ph << 6);
            outp[o2 + (lane >> 1)]      = packh(v0, p0);
            outp[o2 + 32 + (lane >> 1)] = packh(v1, p1);
        }
    }
}

// ---------- K7b: pack pw into f16 pairs (along k) ----------
__global__ __launch_bounds__(256) void k_pw_cvt(const float* __restrict__ pw, unsigned* __restrict__ pwp){
    int i = (blockIdx.x << 10) + (threadIdx.x << 2);
    float4 v = *(const float4*)(pw + i);
    uint2 o;
    o.x = packh(v.x, v.y); o.y = packh(v.z, v.w);
    *(uint2*)(pwp + (i >> 1)) = o;
}

// ---------- K8: projection via f16 MFMA, single product per fragment ----------
__global__ __launch_bounds__(256) void k_proj(const unsigned* __restrict__ cat0, const unsigned* __restrict__ cat1,
                                              const unsigned* __restrict__ pwp, float* __restrict__ out){
    __shared__ unsigned As[128*17];   // [o][k2] f16 pairs along k, stride 17
    __shared__ unsigned Bs[32*65];    // [k][n2] f16 pairs along n, stride 65
    int t = threadIdx.x, lane = t & 63, wave = t >> 6;
    int quad = lane >> 4, l15 = lane & 15;
    int b  = blockIdx.x >> 8;
    int mo = (blockIdx.x >> 7) & 1;
    int nt = blockIdx.x & 127;
    int n0 = nt << 7;
    int n0_2 = nt << 6;
    int wr = (wave >> 1) << 6;
    int wc = (wave & 1) << 6;

    f32x4 acc[4][4];
    #pragma unroll
    for (int i = 0; i < 4; ++i)
        #pragma unroll
        for (int j = 0; j < 4; ++j) acc[i][j] = (f32x4){0.f,0.f,0.f,0.f};

    int ao = t >> 1, ak = (t & 1) << 3;
    int bk = t >> 3, bn8 = (t & 7) << 3;
    int par = l15 & 1;

    for (int ks = 0; ks < 16; ++ks){
        __syncthreads();
        {
            const unsigned* ap = pwp + (size_t)((mo << 7) + ao)*256 + (ks << 4) + ak;
            #pragma unroll
            for (int i = 0; i < 8; ++i) As[ao*17 + ak + i] = ap[i];
        }
        {
            int q = (ks << 5) + bk;
            const unsigned* srow = (q < 256) ? (cat0 + (size_t)((b << 8) + q) * 8192)
                                             : (cat1 + (size_t)((b << 8) + q - 256) * 8192);
            const unsigned* sp_ = srow + n0_2 + bn8;
            *(uint4*)&Bs[bk*65 + bn8]     = *(const uint4*)sp_;
            *(uint4*)&Bs[bk*65 + bn8 + 4] = *(const uint4*)(sp_ + 4);
        }
        __syncthreads();
        FU16 Af[4], Bf[4];
        #pragma unroll
        for (int mi = 0; mi < 4; ++mi){
            const unsigned* ap = &As[(wr + (mi << 4) + l15)*17 + (quad << 2)];
            #pragma unroll
            for (int p = 0; p < 4; ++p) Af[mi].u[p] = ap[p];
        }
        #pragma unroll
        for (int ni = 0; ni < 4; ++ni){
            int n2 = (wc + (ni << 4) + l15) >> 1;
            #pragma unroll
            for (int p = 0; p < 4; ++p){
                unsigned e0 = Bs[((quad << 3) + 2*p)*65 + n2];
                unsigned e1 = Bs[((quad << 3) + 2*p + 1)*65 + n2];
                Bf[ni].u[p] = par ? ((e0 >> 16) | (e1 & 0xFFFF0000u))
                                  : ((e0 & 0xFFFFu) | (e1 << 16));
            }
        }
        #pragma unroll
        for (int mi = 0; mi < 4; ++mi)
            #pragma unroll
            for (int ni = 0; ni < 4; ++ni)
                acc[mi][ni] = __builtin_amdgcn_mfma_f32_16x16x32_f16(Af[mi].v, Bf[ni].v, acc[mi][ni], 0, 0, 0);
    }
    size_t obase = (size_t)((b << 8) + (mo << 7));
    #pragma unroll
    for (int mi = 0; mi < 4; ++mi)
        #pragma unroll
        for (int ni = 0; ni < 4; ++ni){
            int o_ = wr + (mi << 4) + (quad << 2);
            int n_ = n0 + wc + (ni << 4) + l15;
            float* op = out + (obase + o_)*NFFT + n_;
            #pragma unroll
            for (int r = 0; r < 4; ++r) op[(size_t)r*NFFT] = acc[mi][ni][r];
        }
}

// ---------- host ----------
extern "C" void kernel_launch(void* const* d_in, const int* in_sizes, int n_in,
                              void* d_out, int out_size, void* d_ws, size_t ws_size,
                              hipStream_t stream) {
    const float* x    = (const float*)d_in[0];
    const float* temp = (const float*)d_in[1];
    const float* w1   = (const float*)d_in[2];
    const float* b1   = (const float*)d_in[3];
    const float* bg   = (const float*)d_in[4];
    const float* bb_  = (const float*)d_in[5];
    const float* bm   = (const float*)d_in[6];
    const float* bv   = (const float*)d_in[7];
    const float* w2   = (const float*)d_in[8];
    const float* b2   = (const float*)d_in[9];
    const float* pw   = (const float*)d_in[10];
    float* out = (float*)d_out;

    float* ws = (float*)d_ws;
    unsigned* SpecR = (unsigned*)ws;             // fp16 re half-plane, NP/2 u32
    unsigned* SpecI = SpecR + (NP >> 1);         // fp16 im half-plane
    unsigned* Ecat  = (unsigned*)(ws + NP);      // Gpart scratch -> mix out (fp16 cplx), read by ifft_n
    unsigned* Cat0  = (unsigned*)(ws + 2*NP);    // ifft_n out, f16 pairs (8.4M u32)
    unsigned* Cat1  = Cat0 + 8388608;            // ifft2_gate out, f16 pairs (8.4M u32)
    float* norm2 = ws + 3*NP;                    // 1024
    float* G     = norm2 + 1024;                 // 65536
    float* attn2 = G + 65536;                    // 65536
    unsigned* pwpack = (unsigned*)(attn2 + 65536);  // 65536 u32 (f16 pairs)
    float* Gpart = (float*)Ecat;                 // 8 MB scratch, dead until k_mix

    size_t need = (3*NP + 1024 + 65536 + 65536 + 131072) * sizeof(float);
    if (ws_size < need) return;

    k_pw_cvt<<<128, 256, 0, stream>>>(pw, pwpack);
    k_fft2_fwd<<<1024, 1024, 0, stream>>>(x, SpecR, SpecI, norm2);
    k_gram<<<1024, 256, 0, stream>>>(SpecR, SpecI, Gpart);
    k_gram_red<<<256, 256, 0, stream>>>(Gpart, G);
    k_attn<<<32, 256, 0, stream>>>(G, norm2, temp, attn2);
    k_mix<<<1024, 256, 0, stream>>>(SpecR, SpecI, attn2, Ecat);
    k_ifft_n<<<1024, 1024, 0, stream>>>(Ecat, Cat0);
    k_gate<<<1024, 256, 0, stream>>>(SpecR, SpecI, w1, b1, bg, bb_, bm, bv, w2, b2);
    k_ifft2_gate<<<1024, 1024, 0, stream>>>(SpecR, SpecI, Cat1);
    k_proj<<<1024, 256, 0, stream>>>(Cat0, Cat1, pwpack, out);
    (void)in_sizes; (void)n_in; (void)out_size; (void)ws_size;
}

// Round 10
// 428.876 us; speedup vs baseline: 1.5007x; 1.0514x over previous
//
#include <hip/hip_runtime.h>
#include <math.h>

// Problem constants: b=4, c=256, heads=8, c/head=32, h=w=128, n=16384, cr=16
#define NFFT 16384
static constexpr size_t NP = 16777216; // one fp32 plane = 1024 * 16384 floats

typedef short bf16x8 __attribute__((ext_vector_type(8)));
typedef __fp16 f16x8 __attribute__((ext_vector_type(8)));
typedef float f32x4  __attribute__((ext_vector_type(4)));
typedef __fp16 h16x2 __attribute__((ext_vector_type(2)));

union FU  { bf16x8 v; unsigned u[4]; };
union FU16{ f16x8  v; unsigned u[4]; };

// ---------- fast cross-lane xor shuffles (DIT path only; DIF spills with these) ----------
__device__ __forceinline__ float shfx1(float x){
    return __int_as_float(__builtin_amdgcn_mov_dpp(__float_as_int(x), 0xB1, 0xF, 0xF, true));
}
__device__ __forceinline__ float shfx2(float x){
    return __int_as_float(__builtin_amdgcn_mov_dpp(__float_as_int(x), 0x4E, 0xF, 0xF, true));
}
__device__ __forceinline__ float shfx(float x, int m){
    if (m == 1)  return shfx1(x);
    if (m == 2)  return shfx2(x);
    if (m == 4)  return __int_as_float(__builtin_amdgcn_ds_swizzle(__float_as_int(x), 0x101F));
    if (m == 8)  return __int_as_float(__builtin_amdgcn_ds_swizzle(__float_as_int(x), 0x201F));
    if (m == 16) return __int_as_float(__builtin_amdgcn_ds_swizzle(__float_as_int(x), 0x401F));
    return __shfl_xor(x, m, 64);
}

// ---------- helpers ----------
__device__ __forceinline__ void sincos_rev(float rv, float& sn, float& cs){
    sn = __builtin_amdgcn_sinf(rv);   // sin(2*pi*rv)
    cs = __builtin_amdgcn_cosf(rv);
}
__device__ __forceinline__ int rev7(int v){ return (int)(__brev((unsigned)v) >> 25); }

__device__ __forceinline__ unsigned f2bf(float f){
    unsigned u = __float_as_uint(f);
    return (u + 0x7FFFu + ((u >> 16) & 1u)) >> 16;   // round-to-nearest-even
}
__device__ __forceinline__ float bf2f(unsigned h){ return __uint_as_float(h << 16); }

// fp16x2 pack/unpack: packh(a,b) -> (a in LOW 16, b in HIGH 16)
union HU2 { h16x2 h; unsigned u; };
__device__ __forceinline__ unsigned packh(float a, float b){
    HU2 z; z.h = __builtin_amdgcn_cvt_pkrtz(a, b); return z.u;
}
__device__ __forceinline__ void unpackh(unsigned u, float& a, float& b){
    HU2 z; z.u = u; a = (float)z.h.x; b = (float)z.h.y;
}

// ---------- sign/identity-folded per-lane twiddles ----------
struct TwF { float cw[6], sw[6], sg[6], c6, s6; };
__device__ __forceinline__ void make_twf(TwF& t){
    const int l = threadIdx.x & 63;
    #pragma unroll
    for (int lg = 0; lg < 6; ++lg){
        int m = 1 << lg;
        bool up = (l & m) != 0;
        int e = (l & (m-1)) * (64 >> lg);
        float sn, cs; sincos_rev((float)e * 0.0078125f, sn, cs);
        t.cw[lg] = up ? cs : 1.f;
        t.sw[lg] = up ? -sn : 0.f;
        t.sg[lg] = up ? -1.f : 1.f;
    }
    sincos_rev((float)l * 0.0078125f, t.s6, t.c6);
}
// DIT (inverse), select-free: every lane multiplies SELF by folded w, shuffles
// the product, then y = shfl(q) + sg*q.
struct TwI { float cw[6], sw[6], sg[6], c6, s6; };
__device__ __forceinline__ void make_twi(TwI& t){
    const int l = threadIdx.x & 63;
    #pragma unroll
    for (int lg = 0; lg < 6; ++lg){
        int m = 1 << lg;
        bool up = (l & m) != 0;
        int e = (l & (m-1)) * (64 >> lg);
        float sn, cs; sincos_rev((float)e * 0.0078125f, sn, cs);
        t.cw[lg] = up ? cs : 1.f;
        t.sw[lg] = up ? sn : 0.f;
        t.sg[lg] = up ? -1.f : 1.f;
    }
    sincos_rev((float)l * 0.0078125f, t.s6, t.c6);
}

// DIF forward: natural in, slot j holds X[rev7(j)] out. W = e^{-2pi i/128}
// NOTE: plain __shfl_xor here — DPP variant caused scratch spill (R9 post-mortem).
__device__ __forceinline__ void dif128t(const TwF& t, float& r0, float& i0, float& r1, float& i1){
    {
        float ar = r0 + r1, ai = i0 + i1;
        float br = r0 - r1, bi = i0 - i1;
        r0 = ar; i0 = ai;
        r1 =  br*t.c6 + bi*t.s6;
        i1 = -br*t.s6 + bi*t.c6;
    }
    #pragma unroll
    for (int lg = 5; lg >= 0; --lg){
        int m = 1 << lg;
        float cw = t.cw[lg], sw = t.sw[lg], sg = t.sg[lg];
        float pr = __shfl_xor(r0, m, 64), pi = __shfl_xor(i0, m, 64);
        float tr = fmaf(sg, r0, pr), ti = fmaf(sg, i0, pi);
        r0 = tr*cw - ti*sw;
        i0 = tr*sw + ti*cw;
        pr = __shfl_xor(r1, m, 64); pi = __shfl_xor(i1, m, 64);
        tr = fmaf(sg, r1, pr); ti = fmaf(sg, i1, pi);
        r1 = tr*cw - ti*sw;
        i1 = tr*sw + ti*cw;
    }
}

// DIT inverse (unnormalized): slot j holds X[rev7(j)] in, natural out. W = e^{+2pi i/128}
__device__ __forceinline__ void dit128t(const TwI& t, float& r0, float& i0, float& r1, float& i1){
    #pragma unroll
    for (int lg = 0; lg <= 5; ++lg){
        int m = 1 << lg;
        float cw = t.cw[lg], sw = t.sw[lg], sg = t.sg[lg];
        float qr = r0*cw - i0*sw, qi = r0*sw + i0*cw;
        float pr = shfx(qr, m), pi = shfx(qi, m);
        r0 = fmaf(sg, qr, pr);
        i0 = fmaf(sg, qi, pi);
        qr = r1*cw - i1*sw; qi = r1*sw + i1*cw;
        pr = shfx(qr, m); pi = shfx(qi, m);
        r1 = fmaf(sg, qr, pr);
        i1 = fmaf(sg, qi, pi);
    }
    {
        float wr = r1*t.c6 - i1*t.s6, wi = r1*t.s6 + i1*t.c6;
        float ar = r0 + wr, ai = i0 + wi;
        r1 = r0 - wr; i1 = i0 - wi;
        r0 = ar; i0 = ai;
    }
}

// ---------- K1: fused forward fft2 per image -> fp16 half-planes SpecR/SpecI ----------
__global__ __launch_bounds__(1024, 8) void k_fft2_fwd(const float* __restrict__ x,
                                                   unsigned* __restrict__ spR, unsigned* __restrict__ spI,
                                                   float* __restrict__ norm2){
    __shared__ unsigned sp[128*129];
    __shared__ float red[16];
    int lane = threadIdx.x & 63, wave = threadIdx.x >> 6;
    int img = blockIdx.x;
    TwF tw; make_twf(tw);
    const float* base = x + (size_t)img * NFFT;
    #pragma unroll 2
    for (int it = 0; it < 8; ++it){
        int h = (wave << 3) + it;
        float a0 = base[h*128 + lane], b0 = 0.f;
        float a1 = base[h*128 + lane + 64], b1 = 0.f;
        dif128t(tw, a0, b0, a1, b1);
        sp[lane*129 + h]      = packh(a0, b0);
        sp[(lane+64)*129 + h] = packh(a1, b1);
    }
    __syncthreads();
    float acc = 0.f;
    #pragma unroll 2
    for (int it = 0; it < 8; ++it){
        int j = (wave << 3) + it;
        float a0, b0, a1, b1;
        unpackh(sp[j*129 + lane],      a0, b0);
        unpackh(sp[j*129 + lane + 64], a1, b1);
        dif128t(tw, a0, b0, a1, b1);
        acc += a0*a0 + b0*b0 + a1*a1 + b1*b1;
        float t0 = __shfl_xor(a0, 1, 64), u0 = __shfl_xor(b0, 1, 64);
        float t1 = __shfl_xor(a1, 1, 64), u1 = __shfl_xor(b1, 1, 64);
        size_t m = (size_t)img*8192 + (size_t)j*64;
        int k = lane >> 1;
        if (!(lane & 1)){
            spR[m + k]      = packh(a0, t0);
            spR[m + 32 + k] = packh(a1, t1);
        } else {
            spI[m + k]      = packh(u0, b0);
            spI[m + 32 + k] = packh(u1, b1);
        }
    }
    #pragma unroll
    for (int m = 32; m >= 1; m >>= 1) acc += __shfl_xor(acc, m, 64);
    if (lane == 0) red[wave] = acc;
    __syncthreads();
    if (threadIdx.x == 0){
        float s = 0.f;
        #pragma unroll
        for (int i = 0; i < 16; ++i) s += red[i];
        norm2[img] = s;
    }
}

// ---------- K2: gram via f16 MFMA, zero-conversion staging ----------
__global__ __launch_bounds__(256) void k_gram(const unsigned* __restrict__ spR, const unsigned* __restrict__ spI,
                                              float* __restrict__ Gpart){
    __shared__ unsigned lds[2*32*132];
    int t = threadIdx.x, lane = t & 63, wave = t >> 6;
    int bh = blockIdx.x >> 5;
    int ks = blockIdx.x & 31;          // 32 k-splits, K=512 each
    size_t cbase2 = (size_t)bh * 32 * 8192;
    int k0blk = ks << 9;

    int sc = t >> 3, tk = t & 7;

    f32x4 aRe[2][2], aIm[2][2];
    #pragma unroll
    for (int i = 0; i < 2; ++i)
        #pragma unroll
        for (int j = 0; j < 2; ++j){ aRe[i][j] = (f32x4){0,0,0,0}; aIm[i][j] = (f32x4){0,0,0,0}; }

    for (int tile = 0; tile < 2; ++tile){
        int kb = k0blk + (tile << 8);
        __syncthreads();
        {
            const unsigned* pr  = spR + cbase2 + (size_t)sc*8192 + (kb >> 1) + tk*16;
            const unsigned* pi_ = spI + cbase2 + (size_t)sc*8192 + (kb >> 1) + tk*16;
            unsigned* dr = &lds[sc*132 + tk*16];
            unsigned* di = &lds[32*132 + sc*132 + tk*16];
            #pragma unroll
            for (int j = 0; j < 4; ++j){
                *(uint4*)(dr + 4*j) = *(const uint4*)(pr + 4*j);
                *(uint4*)(di + 4*j) = *(const uint4*)(pi_ + 4*j);
            }
        }
        __syncthreads();
        #pragma unroll
        for (int ss = 0; ss < 2; ++ss){
            int s = wave + (ss << 2);
            int kbase = (s << 4) + ((lane >> 4) << 2);
            FU16 fr0, fr1, fi0, fi1, fn0, fn1;
            *(uint4*)fr0.u = *(const uint4*)&lds[ (lane & 15)*132 + kbase ];
            *(uint4*)fr1.u = *(const uint4*)&lds[ ((lane & 15) + 16)*132 + kbase ];
            *(uint4*)fi0.u = *(const uint4*)&lds[ 32*132 + (lane & 15)*132 + kbase ];
            *(uint4*)fi1.u = *(const uint4*)&lds[ 32*132 + ((lane & 15) + 16)*132 + kbase ];
            #pragma unroll
            for (int p = 0; p < 4; ++p){ fn0.u[p] = fi0.u[p] ^ 0x80008000u; fn1.u[p] = fi1.u[p] ^ 0x80008000u; }
            aRe[0][0] = __builtin_amdgcn_mfma_f32_16x16x32_f16(fr0.v, fr0.v, aRe[0][0], 0, 0, 0);
            aRe[0][0] = __builtin_amdgcn_mfma_f32_16x16x32_f16(fn0.v, fi0.v, aRe[0][0], 0, 0, 0);
            aRe[0][1] = __builtin_amdgcn_mfma_f32_16x16x32_f16(fr0.v, fr1.v, aRe[0][1], 0, 0, 0);
            aRe[0][1] = __builtin_amdgcn_mfma_f32_16x16x32_f16(fn0.v, fi1.v, aRe[0][1], 0, 0, 0);
            aRe[1][0] = __builtin_amdgcn_mfma_f32_16x16x32_f16(fr1.v, fr0.v, aRe[1][0], 0, 0, 0);
            aRe[1][0] = __builtin_amdgcn_mfma_f32_16x16x32_f16(fn1.v, fi0.v, aRe[1][0], 0, 0, 0);
            aRe[1][1] = __builtin_amdgcn_mfma_f32_16x16x32_f16(fr1.v, fr1.v, aRe[1][1], 0, 0, 0);
            aRe[1][1] = __builtin_amdgcn_mfma_f32_16x16x32_f16(fn1.v, fi1.v, aRe[1][1], 0, 0, 0);
            aIm[0][0] = __builtin_amdgcn_mfma_f32_16x16x32_f16(fr0.v, fi0.v, aIm[0][0], 0, 0, 0);
            aIm[0][0] = __builtin_amdgcn_mfma_f32_16x16x32_f16(fi0.v, fr0.v, aIm[0][0], 0, 0, 0);
            aIm[0][1] = __builtin_amdgcn_mfma_f32_16x16x32_f16(fr0.v, fi1.v, aIm[0][1], 0, 0, 0);
            aIm[0][1] = __builtin_amdgcn_mfma_f32_16x16x32_f16(fi0.v, fr1.v, aIm[0][1], 0, 0, 0);
            aIm[1][0] = __builtin_amdgcn_mfma_f32_16x16x32_f16(fr1.v, fi0.v, aIm[1][0], 0, 0, 0);
            aIm[1][0] = __builtin_amdgcn_mfma_f32_16x16x32_f16(fi1.v, fr0.v, aIm[1][0], 0, 0, 0);
            aIm[1][1] = __builtin_amdgcn_mfma_f32_16x16x32_f16(fr1.v, fi1.v, aIm[1][1], 0, 0, 0);
            aIm[1][1] = __builtin_amdgcn_mfma_f32_16x16x32_f16(fi1.v, fr1.v, aIm[1][1], 0, 0, 0);
        }
    }
    __syncthreads();
    float* rbuf = (float*)lds;
    int dcol = lane & 15, rrow = lane >> 4;
    #pragma unroll
    for (int i = 0; i < 2; ++i)
        #pragma unroll
        for (int j = 0; j < 2; ++j)
            #pragma unroll
            for (int r = 0; r < 4; ++r){
                int c = (i << 4) + (rrow << 2) + r;
                int d = (j << 4) + dcol;
                rbuf[wave*2048 + ((c << 5) + d)*2    ] = aRe[i][j][r];
                rbuf[wave*2048 + ((c << 5) + d)*2 + 1] = aIm[i][j][r];
            }
    __syncthreads();
    float* gp = Gpart + (size_t)blockIdx.x * 2048;
    for (int idx = t; idx < 2048; idx += 256)
        gp[idx] = rbuf[idx] + rbuf[2048 + idx] + rbuf[4096 + idx] + rbuf[6144 + idx];
}

// ---------- K2b: reduce 32 k-split partials per bh ----------
__global__ __launch_bounds__(256) void k_gram_red(const float* __restrict__ Gpart, float* __restrict__ G){
    int bh = blockIdx.x >> 3;
    int q  = ((blockIdx.x & 7) << 8) + threadIdx.x;
    const float* gp = Gpart + (size_t)bh * 32 * 2048 + q;
    float s = 0.f;
    #pragma unroll 8
    for (int p = 0; p < 32; ++p) s += gp[(size_t)p * 2048];
    G[(size_t)bh * 2048 + q] = s;
}

// ---------- K3: normalize, temperature, complex softmax, fold IF32 * (1/524288) ----------
__global__ __launch_bounds__(256) void k_attn(const float* __restrict__ G, const float* __restrict__ norm2,
                                              const float* __restrict__ temp, float* __restrict__ attn2){
    __shared__ float ar[32*33], ai[32*33];
    int bh = blockIdx.x, h = bh & 7, t = threadIdx.x;
    if (t < 32){
        float tv = temp[h];
        float nc = fmaxf(sqrtf(norm2[(bh<<5) + t]), 1e-12f);
        const float* gr = G + (size_t)bh*2048 + t*64;
        float mr = -1e30f, mi = -1e30f;
        for (int d = 0; d < 32; ++d){
            float nd = fmaxf(sqrtf(norm2[(bh<<5) + d]), 1e-12f);
            float s = tv / (nc * nd);
            float vr = gr[d*2] * s, vi = gr[d*2+1] * s;
            ar[t*33+d] = vr; ai[t*33+d] = vi;
            mr = fmaxf(mr, vr); mi = fmaxf(mi, vi);
        }
        float sr = 0.f, si = 0.f;
        for (int d = 0; d < 32; ++d){
            float er = __expf(ar[t*33+d] - mr), ei = __expf(ai[t*33+d] - mi);
            ar[t*33+d] = er; ai[t*33+d] = ei; sr += er; si += ei;
        }
        sr = 1.f/sr; si = 1.f/si;
        for (int d = 0; d < 32; ++d){ ar[t*33+d] *= sr; ai[t*33+d] *= si; }
    }
    __syncthreads();
    const float S = 1.f / 524288.f;
    for (int q = t; q < 1024; q += 256){
        int e = q >> 5, d = q & 31;
        float sr = 0.f, si = 0.f;
        for (int c = 0; c < 32; ++c){
            float sn, cs; sincos_rev((float)((e*c) & 31) * 0.03125f, sn, cs);
            float xr = ar[c*33+d], xi = ai[c*33+d];
            sr += cs*xr - sn*xi;
            si += cs*xi + sn*xr;
        }
        attn2[(size_t)bh*2048 + q*2]     = sr * S;
        attn2[(size_t)bh*2048 + q*2 + 1] = si * S;
    }
}

// ---------- K4: mix[e][n] = sum_d attn2[e][d] * X[d][n] via f16 MFMA ----------
__global__ __launch_bounds__(256) void k_mix(const unsigned* __restrict__ spR, const unsigned* __restrict__ spI,
                                             const float* __restrict__ attn2,
                                             unsigned* __restrict__ om){
    __shared__ unsigned lds[2*32*36];
    __shared__ float a2s[2048];
    int t = threadIdx.x, lane = t & 63, wave = t >> 6;
    int quad = lane >> 4, l15 = lane & 15;
    int bh = blockIdx.x >> 5;
    int n0 = (blockIdx.x & 31) << 9;
    size_t cbase2 = (size_t)bh * 32 * 8192;
    {
        const float4* s4 = (const float4*)(attn2 + (size_t)bh*2048);
        float4* d4 = (float4*)a2s;
        d4[t] = s4[t]; d4[t + 256] = s4[t + 256];
    }
    __syncthreads();
    FU16 Ar[2], Ai[2];
    #pragma unroll
    for (int et = 0; et < 2; ++et){
        int e = (et << 4) + l15;
        #pragma unroll
        for (int p = 0; p < 4; ++p){
            int d0 = (quad << 3) + (p << 1);
            Ar[et].u[p] = packh(a2s[(e*32 + d0)*2],     a2s[(e*32 + d0 + 1)*2]);
            Ai[et].u[p] = packh(a2s[(e*32 + d0)*2 + 1], a2s[(e*32 + d0 + 1)*2 + 1]);
        }
    }
    int sd = t >> 3, sc4 = (t & 7) << 2;
    for (int tile = 0; tile < 8; ++tile){
        int nb = n0 + (tile << 6);
        __syncthreads();
        {
            size_t g2 = cbase2 + (size_t)sd*8192 + (nb >> 1) + sc4;
            *(uint4*)&lds[sd*36 + sc4]         = *(const uint4*)&spR[g2];
            *(uint4*)&lds[32*36 + sd*36 + sc4] = *(const uint4*)&spI[g2];
        }
        __syncthreads();
        int colb = (wave << 4) + l15;
        int cb2 = colb >> 1; bool codd = colb & 1;
        FU16 Xr, Xi, Xn;
        #pragma unroll
        for (int p = 0; p < 4; ++p){
            int d0 = (quad << 3) + (p << 1);
            unsigned e0 = lds[d0*36 + cb2], e1 = lds[(d0+1)*36 + cb2];
            Xr.u[p] = codd ? ((e0 >> 16) | (e1 & 0xFFFF0000u)) : ((e0 & 0xFFFFu) | (e1 << 16));
            e0 = lds[32*36 + d0*36 + cb2]; e1 = lds[32*36 + (d0+1)*36 + cb2];
            Xi.u[p] = codd ? ((e0 >> 16) | (e1 & 0xFFFF0000u)) : ((e0 & 0xFFFFu) | (e1 << 16));
            Xn.u[p] = Xi.u[p] ^ 0x80008000u;
        }
        #pragma unroll
        for (int et = 0; et < 2; ++et){
            f32x4 ar = (f32x4){0,0,0,0}, ai = (f32x4){0,0,0,0};
            ar = __builtin_amdgcn_mfma_f32_16x16x32_f16(Ar[et].v, Xr.v, ar, 0, 0, 0);
            ar = __builtin_amdgcn_mfma_f32_16x16x32_f16(Ai[et].v, Xn.v, ar, 0, 0, 0);
            ai = __builtin_amdgcn_mfma_f32_16x16x32_f16(Ar[et].v, Xi.v, ai, 0, 0, 0);
            ai = __builtin_amdgcn_mfma_f32_16x16x32_f16(Ai[et].v, Xr.v, ai, 0, 0, 0);
            #pragma unroll
            for (int r = 0; r < 4; ++r){
                int e = (et << 4) + (quad << 2) + r;
                om[cbase2*2 + (size_t)e*NFFT + nb + colb] = packh(ar[r], ai[r]);
            }
        }
    }
}

// ---------- K5: fused 16384-pt inverse FFT + abs per row; fp16-packed complex in, f16 out (packed pairs) ----------
__global__ __launch_bounds__(1024, 8) void k_ifft_n(const unsigned* __restrict__ in, unsigned* __restrict__ outp){
    __shared__ unsigned sp[128*129];
    int lane = threadIdx.x & 63, wave = threadIdx.x >> 6;
    size_t rb = (size_t)blockIdx.x * NFFT;
    TwI tw; make_twi(tw);
    #pragma unroll 2
    for (int it = 0; it < 8; ++it){
        int jw = (wave << 3) + it;
        size_t base = rb + ((size_t)jw << 7);
        float a0, b0, a1, b1;
        unpackh(in[base + lane], a0, b0);
        unpackh(in[base + lane + 64], a1, b1);
        dit128t(tw, a0, b0, a1, b1);
        int kw = rev7(jw);
        float sn, cs;
        sincos_rev((float)(lane * kw) * 6.103515625e-05f, sn, cs);
        float r = a0*cs - b0*sn, i2 = a0*sn + b0*cs;
        sp[lane*129 + jw] = packh(r, i2);
        sincos_rev((float)((lane + 64) * kw) * 6.103515625e-05f, sn, cs);
        r = a1*cs - b1*sn; i2 = a1*sn + b1*cs;
        sp[(lane+64)*129 + jw] = packh(r, i2);
    }
    __syncthreads();
    float av0[8], av1[8];
    #pragma unroll
    for (int it = 0; it < 8; ++it){
        int pw = (wave << 3) + it;
        float a0, b0, a1, b1;
        unpackh(sp[pw*129 + lane],      a0, b0);
        unpackh(sp[pw*129 + lane + 64], a1, b1);
        dit128t(tw, a0, b0, a1, b1);
        av0[it] = sqrtf(a0*a0 + b0*b0);
        av1[it] = sqrtf(a1*a1 + b1*b1);
    }
    __syncthreads();
    // transpose via LDS at half width: u32 holds f16 pair of adjacent columns (pw, pw+1)
    #pragma unroll
    for (int p = 0; p < 4; ++p){
        sp[lane*65 + (wave << 2) + p]      = packh(av0[2*p], av0[2*p+1]);
        sp[(lane+64)*65 + (wave << 2) + p] = packh(av1[2*p], av1[2*p+1]);
    }
    __syncthreads();
    int row = threadIdx.x >> 3, cb = (threadIdx.x & 7) << 3;
    unsigned* ob = outp + ((size_t)blockIdx.x << 13) + row*64 + cb;
    const unsigned* s = &sp[row*65 + cb];
    *(uint4*)(ob)     = make_uint4(s[0], s[1], s[2], s[3]);
    *(uint4*)(ob + 4) = make_uint4(s[4], s[5], s[6], s[7]);
}

// ---------- K6: gating, IN-PLACE on fp16 half-planes ----------
__global__ __launch_bounds__(256) void k_gate(unsigned* spR, unsigned* spI,
                                              const float* __restrict__ w1, const float* __restrict__ b1,
                                              const float* __restrict__ bg, const float* __restrict__ bb_,
                                              const float* __restrict__ bm, const float* __restrict__ bv,
                                              const float* __restrict__ w2, const float* __restrict__ b2){
    __shared__ float w1T[256*17];
    __shared__ float w2s[256*16];
    __shared__ float yred[256*17];
    int t = threadIdx.x, g = t >> 6, col = t & 63;
    #pragma unroll
    for (int i = 0; i < 16; ++i) w1T[t*17 + i] = w1[i*256 + t];
    {
        const float4* s4 = (const float4*)w2; float4* d4 = (float4*)w2s;
        #pragma unroll
        for (int i = 0; i < 4; ++i) d4[i*256 + t] = s4[i*256 + t];
    }
    __syncthreads();
    int b = blockIdx.x >> 8;
    int n = ((blockIdx.x & 255) << 6) + col;
    int odd = n & 1;
    size_t base2 = (((size_t)b << 8) << 13) + (n >> 1);
    float y[16];
    #pragma unroll
    for (int r = 0; r < 16; ++r) y[r] = 0.f;
    for (int c = g << 6; c < (g << 6) + 64; ++c){
        float lo, hi; unpackh(spR[base2 + ((size_t)c << 13)], lo, hi);
        float xr = odd ? hi : lo;
        #pragma unroll
        for (int r = 0; r < 16; ++r) y[r] += w1T[c*17 + r] * xr;
    }
    #pragma unroll
    for (int r = 0; r < 16; ++r) yred[t*17 + r] = y[r];
    __syncthreads();
    #pragma unroll
    for (int r = 0; r < 16; ++r){
        float v = yred[col*17 + r] + yred[(col+64)*17 + r]
                + yred[(col+128)*17 + r] + yred[(col+192)*17 + r] + b1[r];
        v = (v - bm[r]) * rsqrtf(bv[r] + 1e-5f) * bg[r] + bb_[r];
        y[r] = fmaxf(v, 0.f);
    }
    for (int o = g << 6; o < (g << 6) + 64; ++o){
        float s = b2[o];
        #pragma unroll
        for (int r = 0; r < 16; ++r) s += w2s[o*16 + r] * y[r];
        float gg = 1.f / (1.f + __expf(-s)) * 6.103515625e-05f;   // sigmoid * 1/16384
        float ggN = shfx1(gg);
        size_t mi = base2 + ((size_t)o << 13);
        if (!odd){
            float lo, hi; unpackh(spR[mi], lo, hi);
            spR[mi] = packh(gg*lo, ggN*hi);
        } else {
            float lo, hi; unpackh(spI[mi], lo, hi);
            spI[mi] = packh(ggN*lo, gg*hi);
        }
    }
}

// ---------- K7: fused ifft2 per image + abs -> f16 (packed pairs) into Cat1 ----------
__global__ __launch_bounds__(1024, 8) void k_ifft2_gate(const unsigned* __restrict__ spR,
                                                        const unsigned* __restrict__ spI,
                                                        unsigned* __restrict__ outp){
    __shared__ unsigned sp[128*129];
    int lane = threadIdx.x & 63, wave = threadIdx.x >> 6;
    TwI tw; make_twi(tw);
    size_t ib = (size_t)blockIdx.x * NFFT;
    #pragma unroll 2
    for (int it = 0; it < 8; ++it){
        int jw = (wave << 3) + it;
        size_t m = (ib + ((size_t)jw << 7)) >> 1;
        int k = lane >> 1; bool od = lane & 1;
        float lo, hi, a0, b0, a1, b1;
        unpackh(spR[m + k], lo, hi);      a0 = od ? hi : lo;
        unpackh(spI[m + k], lo, hi);      b0 = od ? hi : lo;
        unpackh(spR[m + 32 + k], lo, hi); a1 = od ? hi : lo;
        unpackh(spI[m + 32 + k], lo, hi); b1 = od ? hi : lo;
        dit128t(tw, a0, b0, a1, b1);
        sp[lane*129 + jw]      = packh(a0, b0);
        sp[(lane+64)*129 + jw] = packh(a1, b1);
    }
    __syncthreads();
    #pragma unroll 2
    for (int it = 0; it < 8; ++it){
        int ph = (wave << 3) + it;
        float a0, b0, a1, b1;
        unpackh(sp[ph*129 + lane],      a0, b0);
        unpackh(sp[ph*129 + lane + 64], a1, b1);
        dit128t(tw, a0, b0, a1, b1);
        float v0 = sqrtf(a0*a0 + b0*b0), v1 = sqrtf(a1*a1 + b1*b1);
        float p0 = shfx1(v0), p1 = shfx1(v1);
        if (!(lane & 1)){
            size_t o2 = ((size_t)blockIdx.x << 13) + (ph << 6);
            outp[o2 + (lane >> 1)]      = packh(v0, p0);
            outp[o2 + 32 + (lane >> 1)] = packh(v1, p1);
        }
    }
}

// ---------- K7b: pack pw into f16 pairs (along k) ----------
__global__ __launch_bounds__(256) void k_pw_cvt(const float* __restrict__ pw, unsigned* __restrict__ pwp){
    int i = (blockIdx.x << 10) + (threadIdx.x << 2);
    float4 v = *(const float4*)(pw + i);
    uint2 o;
    o.x = packh(v.x, v.y); o.y = packh(v.z, v.w);
    *(uint2*)(pwp + (i >> 1)) = o;
}

// ---------- K8: projection via f16 MFMA, single product per fragment ----------
__global__ __launch_bounds__(256) void k_proj(const unsigned* __restrict__ cat0, const unsigned* __restrict__ cat1,
                                              const unsigned* __restrict__ pwp, float* __restrict__ out){
    __shared__ unsigned As[128*17];   // [o][k2] f16 pairs along k, stride 17
    __shared__ unsigned Bs[32*65];    // [k][n2] f16 pairs along n, stride 65
    int t = threadIdx.x, lane = t & 63, wave = t >> 6;
    int quad = lane >> 4, l15 = lane & 15;
    int b  = blockIdx.x >> 8;
    int mo = (blockIdx.x >> 7) & 1;
    int nt = blockIdx.x & 127;
    int n0 = nt << 7;
    int n0_2 = nt << 6;
    int wr = (wave >> 1) << 6;
    int wc = (wave & 1) << 6;

    f32x4 acc[4][4];
    #pragma unroll
    for (int i = 0; i < 4; ++i)
        #pragma unroll
        for (int j = 0; j < 4; ++j) acc[i][j] = (f32x4){0.f,0.f,0.f,0.f};

    int ao = t >> 1, ak = (t & 1) << 3;
    int bk = t >> 3, bn8 = (t & 7) << 3;
    int par = l15 & 1;

    for (int ks = 0; ks < 16; ++ks){
        __syncthreads();
        {
            const unsigned* ap = pwp + (size_t)((mo << 7) + ao)*256 + (ks << 4) + ak;
            #pragma unroll
            for (int i = 0; i < 8; ++i) As[ao*17 + ak + i] = ap[i];
        }
        {
            int q = (ks << 5) + bk;
            const unsigned* srow = (q < 256) ? (cat0 + (size_t)((b << 8) + q) * 8192)
                                             : (cat1 + (size_t)((b << 8) + q - 256) * 8192);
            const unsigned* sp_ = srow + n0_2 + bn8;
            *(uint4*)&Bs[bk*65 + bn8]     = *(const uint4*)sp_;
            *(uint4*)&Bs[bk*65 + bn8 + 4] = *(const uint4*)(sp_ + 4);
        }
        __syncthreads();
        FU16 Af[4], Bf[4];
        #pragma unroll
        for (int mi = 0; mi < 4; ++mi){
            const unsigned* ap = &As[(wr + (mi << 4) + l15)*17 + (quad << 2)];
            #pragma unroll
            for (int p = 0; p < 4; ++p) Af[mi].u[p] = ap[p];
        }
        #pragma unroll
        for (int ni = 0; ni < 4; ++ni){
            int n2 = (wc + (ni << 4) + l15) >> 1;
            #pragma unroll
            for (int p = 0; p < 4; ++p){
                unsigned e0 = Bs[((quad << 3) + 2*p)*65 + n2];
                unsigned e1 = Bs[((quad << 3) + 2*p + 1)*65 + n2];
                Bf[ni].u[p] = par ? ((e0 >> 16) | (e1 & 0xFFFF0000u))
                                  : ((e0 & 0xFFFFu) | (e1 << 16));
            }
        }
        #pragma unroll
        for (int mi = 0; mi < 4; ++mi)
            #pragma unroll
            for (int ni = 0; ni < 4; ++ni)
                acc[mi][ni] = __builtin_amdgcn_mfma_f32_16x16x32_f16(Af[mi].v, Bf[ni].v, acc[mi][ni], 0, 0, 0);
    }
    size_t obase = (size_t)((b << 8) + (mo << 7));
    #pragma unroll
    for (int mi = 0; mi < 4; ++mi)
        #pragma unroll
        for (int ni = 0; ni < 4; ++ni){
            int o_ = wr + (mi << 4) + (quad << 2);
            int n_ = n0 + wc + (ni << 4) + l15;
            float* op = out + (obase + o_)*NFFT + n_;
            #pragma unroll
            for (int r = 0; r < 4; ++r) op[(size_t)r*NFFT] = acc[mi][ni][r];
        }
}

// ---------- host ----------
extern "C" void kernel_launch(void* const* d_in, const int* in_sizes, int n_in,
                              void* d_out, int out_size, void* d_ws, size_t ws_size,
                              hipStream_t stream) {
    const float* x    = (const float*)d_in[0];
    const float* temp = (const float*)d_in[1];
    const float* w1   = (const float*)d_in[2];
    const float* b1   = (const float*)d_in[3];
    const float* bg   = (const float*)d_in[4];
    const float* bb_  = (const float*)d_in[5];
    const float* bm   = (const float*)d_in[6];
    const float* bv   = (const float*)d_in[7];
    const float* w2   = (const float*)d_in[8];
    const float* b2   = (const float*)d_in[9];
    const float* pw   = (const float*)d_in[10];
    float* out = (float*)d_out;

    float* ws = (float*)d_ws;
    unsigned* SpecR = (unsigned*)ws;             // fp16 re half-plane, NP/2 u32
    unsigned* SpecI = SpecR + (NP >> 1);         // fp16 im half-plane
    unsigned* Ecat  = (unsigned*)(ws + NP);      // Gpart scratch -> mix out (fp16 cplx), read by ifft_n
    unsigned* Cat0  = (unsigned*)(ws + 2*NP);    // ifft_n out, f16 pairs (8.4M u32)
    unsigned* Cat1  = Cat0 + 8388608;            // ifft2_gate out, f16 pairs (8.4M u32)
    float* norm2 = ws + 3*NP;                    // 1024
    float* G     = norm2 + 1024;                 // 65536
    float* attn2 = G + 65536;                    // 65536
    unsigned* pwpack = (unsigned*)(attn2 + 65536);  // 65536 u32 (f16 pairs)
    float* Gpart = (float*)Ecat;                 // 8 MB scratch, dead until k_mix

    size_t need = (3*NP + 1024 + 65536 + 65536 + 131072) * sizeof(float);
    if (ws_size < need) return;

    k_pw_cvt<<<128, 256, 0, stream>>>(pw, pwpack);
    k_fft2_fwd<<<1024, 1024, 0, stream>>>(x, SpecR, SpecI, norm2);
    k_gram<<<1024, 256, 0, stream>>>(SpecR, SpecI, Gpart);
    k_gram_red<<<256, 256, 0, stream>>>(Gpart, G);
    k_attn<<<32, 256, 0, stream>>>(G, norm2, temp, attn2);
    k_mix<<<1024, 256, 0, stream>>>(SpecR, SpecI, attn2, Ecat);
    k_ifft_n<<<1024, 1024, 0, stream>>>(Ecat, Cat0);
    k_gate<<<1024, 256, 0, stream>>>(SpecR, SpecI, w1, b1, bg, bb_, bm, bv, w2, b2);
    k_ifft2_gate<<<1024, 1024, 0, stream>>>(SpecR, SpecI, Cat1);
    k_proj<<<1024, 256, 0, stream>>>(Cat0, Cat1, pwpack, out);
    (void)in_sizes; (void)n_in; (void)out_size; (void)ws_size;
}

// Round 12
// 416.072 us; speedup vs baseline: 1.5469x; 1.0308x over previous
//
#include <hip/hip_runtime.h>
#include <math.h>

// Problem constants: b=4, c=256, heads=8, c/head=32, h=w=128, n=16384, cr=16
#define NFFT 16384
static constexpr size_t NP = 16777216; // one fp32 plane = 1024 * 16384 floats

typedef short bf16x8 __attribute__((ext_vector_type(8)));
typedef __fp16 f16x8 __attribute__((ext_vector_type(8)));
typedef float f32x4  __attribute__((ext_vector_type(4)));
typedef __fp16 h16x2 __attribute__((ext_vector_type(2)));

union FU  { bf16x8 v; unsigned u[4]; };
union FU16{ f16x8  v; unsigned u[4]; };

// ---------- fast cross-lane xor shuffles (DIT path only; DIF spills with these) ----------
__device__ __forceinline__ float shfx1(float x){
    return __int_as_float(__builtin_amdgcn_mov_dpp(__float_as_int(x), 0xB1, 0xF, 0xF, true));
}
__device__ __forceinline__ float shfx2(float x){
    return __int_as_float(__builtin_amdgcn_mov_dpp(__float_as_int(x), 0x4E, 0xF, 0xF, true));
}
__device__ __forceinline__ float shfx(float x, int m){
    if (m == 1)  return shfx1(x);
    if (m == 2)  return shfx2(x);
    if (m == 4)  return __int_as_float(__builtin_amdgcn_ds_swizzle(__float_as_int(x), 0x101F));
    if (m == 8)  return __int_as_float(__builtin_amdgcn_ds_swizzle(__float_as_int(x), 0x201F));
    if (m == 16) return __int_as_float(__builtin_amdgcn_ds_swizzle(__float_as_int(x), 0x401F));
    return __shfl_xor(x, m, 64);
}

// ---------- helpers ----------
__device__ __forceinline__ void sincos_rev(float rv, float& sn, float& cs){
    sn = __builtin_amdgcn_sinf(rv);   // sin(2*pi*rv)
    cs = __builtin_amdgcn_cosf(rv);
}
__device__ __forceinline__ int rev7(int v){ return (int)(__brev((unsigned)v) >> 25); }

__device__ __forceinline__ unsigned f2bf(float f){
    unsigned u = __float_as_uint(f);
    return (u + 0x7FFFu + ((u >> 16) & 1u)) >> 16;   // round-to-nearest-even
}
__device__ __forceinline__ float bf2f(unsigned h){ return __uint_as_float(h << 16); }

// fp16x2 pack/unpack: packh(a,b) -> (a in LOW 16, b in HIGH 16)
union HU2 { h16x2 h; unsigned u; };
__device__ __forceinline__ unsigned packh(float a, float b){
    HU2 z; z.h = __builtin_amdgcn_cvt_pkrtz(a, b); return z.u;
}
__device__ __forceinline__ void unpackh(unsigned u, float& a, float& b){
    HU2 z; z.u = u; a = (float)z.h.x; b = (float)z.h.y;
}

// ---------- sign/identity-folded per-lane twiddles ----------
struct TwF { float cw[6], sw[6], sg[6], c6, s6; };
__device__ __forceinline__ void make_twf(TwF& t){
    const int l = threadIdx.x & 63;
    #pragma unroll
    for (int lg = 0; lg < 6; ++lg){
        int m = 1 << lg;
        bool up = (l & m) != 0;
        int e = (l & (m-1)) * (64 >> lg);
        float sn, cs; sincos_rev((float)e * 0.0078125f, sn, cs);
        t.cw[lg] = up ? cs : 1.f;
        t.sw[lg] = up ? -sn : 0.f;
        t.sg[lg] = up ? -1.f : 1.f;
    }
    sincos_rev((float)l * 0.0078125f, t.s6, t.c6);
}
// DIT (inverse), select-free: every lane multiplies SELF by folded w, shuffles
// the product, then y = shfl(q) + sg*q.
struct TwI { float cw[6], sw[6], sg[6], c6, s6; };
__device__ __forceinline__ void make_twi(TwI& t){
    const int l = threadIdx.x & 63;
    #pragma unroll
    for (int lg = 0; lg < 6; ++lg){
        int m = 1 << lg;
        bool up = (l & m) != 0;
        int e = (l & (m-1)) * (64 >> lg);
        float sn, cs; sincos_rev((float)e * 0.0078125f, sn, cs);
        t.cw[lg] = up ? cs : 1.f;
        t.sw[lg] = up ? sn : 0.f;
        t.sg[lg] = up ? -1.f : 1.f;
    }
    sincos_rev((float)l * 0.0078125f, t.s6, t.c6);
}

// DIF forward: natural in, slot j holds X[rev7(j)] out. W = e^{-2pi i/128}
// NOTE: plain __shfl_xor here — DPP variant caused scratch spill (R9 post-mortem).
__device__ __forceinline__ void dif128t(const TwF& t, float& r0, float& i0, float& r1, float& i1){
    {
        float ar = r0 + r1, ai = i0 + i1;
        float br = r0 - r1, bi = i0 - i1;
        r0 = ar; i0 = ai;
        r1 =  br*t.c6 + bi*t.s6;
        i1 = -br*t.s6 + bi*t.c6;
    }
    #pragma unroll
    for (int lg = 5; lg >= 0; --lg){
        int m = 1 << lg;
        float cw = t.cw[lg], sw = t.sw[lg], sg = t.sg[lg];
        float pr = __shfl_xor(r0, m, 64), pi = __shfl_xor(i0, m, 64);
        float tr = fmaf(sg, r0, pr), ti = fmaf(sg, i0, pi);
        r0 = tr*cw - ti*sw;
        i0 = tr*sw + ti*cw;
        pr = __shfl_xor(r1, m, 64); pi = __shfl_xor(i1, m, 64);
        tr = fmaf(sg, r1, pr); ti = fmaf(sg, i1, pi);
        r1 = tr*cw - ti*sw;
        i1 = tr*sw + ti*cw;
    }
}

// DIT inverse (unnormalized): slot j holds X[rev7(j)] in, natural out. W = e^{+2pi i/128}
__device__ __forceinline__ void dit128t(const TwI& t, float& r0, float& i0, float& r1, float& i1){
    #pragma unroll
    for (int lg = 0; lg <= 5; ++lg){
        int m = 1 << lg;
        float cw = t.cw[lg], sw = t.sw[lg], sg = t.sg[lg];
        float qr = r0*cw - i0*sw, qi = r0*sw + i0*cw;
        float pr = shfx(qr, m), pi = shfx(qi, m);
        r0 = fmaf(sg, qr, pr);
        i0 = fmaf(sg, qi, pi);
        qr = r1*cw - i1*sw; qi = r1*sw + i1*cw;
        pr = shfx(qr, m); pi = shfx(qi, m);
        r1 = fmaf(sg, qr, pr);
        i1 = fmaf(sg, qi, pi);
    }
    {
        float wr = r1*t.c6 - i1*t.s6, wi = r1*t.s6 + i1*t.c6;
        float ar = r0 + wr, ai = i0 + wi;
        r1 = r0 - wr; i1 = i0 - wi;
        r0 = ar; i0 = ai;
    }
}

// ---------- K1: fused forward fft2 per image -> fp16 half-planes SpecR/SpecI ----------
// Real-input two-for-one: pass 1 FFTs packed rows (x[h] + i*x[h+64]) — half the
// butterflies. Hermitian unpack deferred to pass 2 via fixed LDS column pairs
// (partner column pj = rev7(128 - rev7(j)) — no cross-lane ops).
__global__ __launch_bounds__(1024, 8) void k_fft2_fwd(const float* __restrict__ x,
                                                   unsigned* __restrict__ spR, unsigned* __restrict__ spI,
                                                   float* __restrict__ norm2){
    __shared__ unsigned sp[128*65];   // [slot-col][zrow], packed Z rows, 33.3 KB
    __shared__ float red[16];
    int lane = threadIdx.x & 63, wave = threadIdx.x >> 6;
    int img = blockIdx.x;
    TwF tw; make_twf(tw);
    const float* base = x + (size_t)img * NFFT;
    #pragma unroll 2
    for (int it = 0; it < 4; ++it){
        int h = (wave << 2) + it;                    // packed row: true rows h, h+64
        float a0 = base[h*128 + lane];
        float b0 = base[(h+64)*128 + lane];
        float a1 = base[h*128 + lane + 64];
        float b1 = base[(h+64)*128 + lane + 64];
        dif128t(tw, a0, b0, a1, b1);
        sp[lane*65 + h]      = packh(a0, b0);
        sp[(lane+64)*65 + h] = packh(a1, b1);
    }
    __syncthreads();
    float acc = 0.f;
    #pragma unroll 2
    for (int it = 0; it < 8; ++it){
        int j = (wave << 3) + it;                    // slot column (w-freq rev7(j))
        int pj = rev7((128 - rev7(j)) & 127);        // negated-frequency partner slot
        float zr, zi, pr, pi;
        unpackh(sp[j*65 + lane],  zr, zi);
        unpackh(sp[pj*65 + lane], pr, pi);
        // row lane   (Xa = (Z + conj(Zn))/2), row lane+64 (Xb = -i(Z - conj(Zn))/2)
        float a0 = 0.5f*(zr + pr);
        float b0 = 0.5f*(zi - pi);
        float a1 = 0.5f*(zi + pi);
        float b1 = 0.5f*(pr - zr);
        dif128t(tw, a0, b0, a1, b1);
        acc += a0*a0 + b0*b0 + a1*a1 + b1*b1;
        float t0 = __shfl_xor(a0, 1, 64), u0 = __shfl_xor(b0, 1, 64);
        float t1 = __shfl_xor(a1, 1, 64), u1 = __shfl_xor(b1, 1, 64);
        size_t m = (size_t)img*8192 + (size_t)j*64;
        int k = lane >> 1;
        if (!(lane & 1)){
            spR[m + k]      = packh(a0, t0);
            spR[m + 32 + k] = packh(a1, t1);
        } else {
            spI[m + k]      = packh(u0, b0);
            spI[m + 32 + k] = packh(u1, b1);
        }
    }
    #pragma unroll
    for (int m = 32; m >= 1; m >>= 1) acc += __shfl_xor(acc, m, 64);
    if (lane == 0) red[wave] = acc;
    __syncthreads();
    if (threadIdx.x == 0){
        float s = 0.f;
        #pragma unroll
        for (int i = 0; i < 16; ++i) s += red[i];
        norm2[img] = s;
    }
}

// ---------- K2: gram via f16 MFMA, zero-conversion staging ----------
__global__ __launch_bounds__(256) void k_gram(const unsigned* __restrict__ spR, const unsigned* __restrict__ spI,
                                              float* __restrict__ Gpart){
    __shared__ unsigned lds[2*32*132];
    int t = threadIdx.x, lane = t & 63, wave = t >> 6;
    int bh = blockIdx.x >> 5;
    int ks = blockIdx.x & 31;          // 32 k-splits, K=512 each
    size_t cbase2 = (size_t)bh * 32 * 8192;
    int k0blk = ks << 9;

    int sc = t >> 3, tk = t & 7;

    f32x4 aRe[2][2], aIm[2][2];
    #pragma unroll
    for (int i = 0; i < 2; ++i)
        #pragma unroll
        for (int j = 0; j < 2; ++j){ aRe[i][j] = (f32x4){0,0,0,0}; aIm[i][j] = (f32x4){0,0,0,0}; }

    for (int tile = 0; tile < 2; ++tile){
        int kb = k0blk + (tile << 8);
        __syncthreads();
        {
            const unsigned* pr  = spR + cbase2 + (size_t)sc*8192 + (kb >> 1) + tk*16;
            const unsigned* pi_ = spI + cbase2 + (size_t)sc*8192 + (kb >> 1) + tk*16;
            unsigned* dr = &lds[sc*132 + tk*16];
            unsigned* di = &lds[32*132 + sc*132 + tk*16];
            #pragma unroll
            for (int j = 0; j < 4; ++j){
                *(uint4*)(dr + 4*j) = *(const uint4*)(pr + 4*j);
                *(uint4*)(di + 4*j) = *(const uint4*)(pi_ + 4*j);
            }
        }
        __syncthreads();
        #pragma unroll
        for (int ss = 0; ss < 2; ++ss){
            int s = wave + (ss << 2);
            int kbase = (s << 4) + ((lane >> 4) << 2);
            FU16 fr0, fr1, fi0, fi1, fn0, fn1;
            *(uint4*)fr0.u = *(const uint4*)&lds[ (lane & 15)*132 + kbase ];
            *(uint4*)fr1.u = *(const uint4*)&lds[ ((lane & 15) + 16)*132 + kbase ];
            *(uint4*)fi0.u = *(const uint4*)&lds[ 32*132 + (lane & 15)*132 + kbase ];
            *(uint4*)fi1.u = *(const uint4*)&lds[ 32*132 + ((lane & 15) + 16)*132 + kbase ];
            #pragma unroll
            for (int p = 0; p < 4; ++p){ fn0.u[p] = fi0.u[p] ^ 0x80008000u; fn1.u[p] = fi1.u[p] ^ 0x80008000u; }
            aRe[0][0] = __builtin_amdgcn_mfma_f32_16x16x32_f16(fr0.v, fr0.v, aRe[0][0], 0, 0, 0);
            aRe[0][0] = __builtin_amdgcn_mfma_f32_16x16x32_f16(fn0.v, fi0.v, aRe[0][0], 0, 0, 0);
            aRe[0][1] = __builtin_amdgcn_mfma_f32_16x16x32_f16(fr0.v, fr1.v, aRe[0][1], 0, 0, 0);
            aRe[0][1] = __builtin_amdgcn_mfma_f32_16x16x32_f16(fn0.v, fi1.v, aRe[0][1], 0, 0, 0);
            aRe[1][0] = __builtin_amdgcn_mfma_f32_16x16x32_f16(fr1.v, fr0.v, aRe[1][0], 0, 0, 0);
            aRe[1][0] = __builtin_amdgcn_mfma_f32_16x16x32_f16(fn1.v, fi0.v, aRe[1][0], 0, 0, 0);
            aRe[1][1] = __builtin_amdgcn_mfma_f32_16x16x32_f16(fr1.v, fr1.v, aRe[1][1], 0, 0, 0);
            aRe[1][1] = __builtin_amdgcn_mfma_f32_16x16x32_f16(fn1.v, fi1.v, aRe[1][1], 0, 0, 0);
            aIm[0][0] = __builtin_amdgcn_mfma_f32_16x16x32_f16(fr0.v, fi0.v, aIm[0][0], 0, 0, 0);
            aIm[0][0] = __builtin_amdgcn_mfma_f32_16x16x32_f16(fi0.v, fr0.v, aIm[0][0], 0, 0, 0);
            aIm[0][1] = __builtin_amdgcn_mfma_f32_16x16x32_f16(fr0.v, fi1.v, aIm[0][1], 0, 0, 0);
            aIm[0][1] = __builtin_amdgcn_mfma_f32_16x16x32_f16(fi0.v, fr1.v, aIm[0][1], 0, 0, 0);
            aIm[1][0] = __builtin_amdgcn_mfma_f32_16x16x32_f16(fr1.v, fi0.v, aIm[1][0], 0, 0, 0);
            aIm[1][0] = __builtin_amdgcn_mfma_f32_16x16x32_f16(fi1.v, fr0.v, aIm[1][0], 0, 0, 0);
            aIm[1][1] = __builtin_amdgcn_mfma_f32_16x16x32_f16(fr1.v, fi1.v, aIm[1][1], 0, 0, 0);
            aIm[1][1] = __builtin_amdgcn_mfma_f32_16x16x32_f16(fi1.v, fr1.v, aIm[1][1], 0, 0, 0);
        }
    }
    __syncthreads();
    float* rbuf = (float*)lds;
    int dcol = lane & 15, rrow = lane >> 4;
    #pragma unroll
    for (int i = 0; i < 2; ++i)
        #pragma unroll
        for (int j = 0; j < 2; ++j)
            #pragma unroll
            for (int r = 0; r < 4; ++r){
                int c = (i << 4) + (rrow << 2) + r;
                int d = (j << 4) + dcol;
                rbuf[wave*2048 + ((c << 5) + d)*2    ] = aRe[i][j][r];
                rbuf[wave*2048 + ((c << 5) + d)*2 + 1] = aIm[i][j][r];
            }
    __syncthreads();
    float* gp = Gpart + (size_t)blockIdx.x * 2048;
    for (int idx = t; idx < 2048; idx += 256)
        gp[idx] = rbuf[idx] + rbuf[2048 + idx] + rbuf[4096 + idx] + rbuf[6144 + idx];
}

// ---------- K2b: reduce 32 k-split partials per bh ----------
__global__ __launch_bounds__(256) void k_gram_red(const float* __restrict__ Gpart, float* __restrict__ G){
    int bh = blockIdx.x >> 3;
    int q  = ((blockIdx.x & 7) << 8) + threadIdx.x;
    const float* gp = Gpart + (size_t)bh * 32 * 2048 + q;
    float s = 0.f;
    #pragma unroll 8
    for (int p = 0; p < 32; ++p) s += gp[(size_t)p * 2048];
    G[(size_t)bh * 2048 + q] = s;
}

// ---------- K3: normalize, temperature, complex softmax, fold IF32 * (1/524288) ----------
__global__ __launch_bounds__(256) void k_attn(const float* __restrict__ G, const float* __restrict__ norm2,
                                              const float* __restrict__ temp, float* __restrict__ attn2){
    __shared__ float ar[32*33], ai[32*33];
    int bh = blockIdx.x, h = bh & 7, t = threadIdx.x;
    if (t < 32){
        float tv = temp[h];
        float nc = fmaxf(sqrtf(norm2[(bh<<5) + t]), 1e-12f);
        const float* gr = G + (size_t)bh*2048 + t*64;
        float mr = -1e30f, mi = -1e30f;
        for (int d = 0; d < 32; ++d){
            float nd = fmaxf(sqrtf(norm2[(bh<<5) + d]), 1e-12f);
            float s = tv / (nc * nd);
            float vr = gr[d*2] * s, vi = gr[d*2+1] * s;
            ar[t*33+d] = vr; ai[t*33+d] = vi;
            mr = fmaxf(mr, vr); mi = fmaxf(mi, vi);
        }
        float sr = 0.f, si = 0.f;
        for (int d = 0; d < 32; ++d){
            float er = __expf(ar[t*33+d] - mr), ei = __expf(ai[t*33+d] - mi);
            ar[t*33+d] = er; ai[t*33+d] = ei; sr += er; si += ei;
        }
        sr = 1.f/sr; si = 1.f/si;
        for (int d = 0; d < 32; ++d){ ar[t*33+d] *= sr; ai[t*33+d] *= si; }
    }
    __syncthreads();
    const float S = 1.f / 524288.f;
    for (int q = t; q < 1024; q += 256){
        int e = q >> 5, d = q & 31;
        float sr = 0.f, si = 0.f;
        for (int c = 0; c < 32; ++c){
            float sn, cs; sincos_rev((float)((e*c) & 31) * 0.03125f, sn, cs);
            float xr = ar[c*33+d], xi = ai[c*33+d];
            sr += cs*xr - sn*xi;
            si += cs*xi + sn*xr;
        }
        attn2[(size_t)bh*2048 + q*2]     = sr * S;
        attn2[(size_t)bh*2048 + q*2 + 1] = si * S;
    }
}

// ---------- K4: mix[e][n] = sum_d attn2[e][d] * X[d][n] via f16 MFMA ----------
__global__ __launch_bounds__(256) void k_mix(const unsigned* __restrict__ spR, const unsigned* __restrict__ spI,
                                             const float* __restrict__ attn2,
                                             unsigned* __restrict__ om){
    __shared__ unsigned lds[2*32*36];
    __shared__ float a2s[2048];
    int t = threadIdx.x, lane = t & 63, wave = t >> 6;
    int quad = lane >> 4, l15 = lane & 15;
    int bh = blockIdx.x >> 5;
    int n0 = (blockIdx.x & 31) << 9;
    size_t cbase2 = (size_t)bh * 32 * 8192;
    {
        const float4* s4 = (const float4*)(attn2 + (size_t)bh*2048);
        float4* d4 = (float4*)a2s;
        d4[t] = s4[t]; d4[t + 256] = s4[t + 256];
    }
    __syncthreads();
    FU16 Ar[2], Ai[2];
    #pragma unroll
    for (int et = 0; et < 2; ++et){
        int e = (et << 4) + l15;
        #pragma unroll
        for (int p = 0; p < 4; ++p){
            int d0 = (quad << 3) + (p << 1);
            Ar[et].u[p] = packh(a2s[(e*32 + d0)*2],     a2s[(e*32 + d0 + 1)*2]);
            Ai[et].u[p] = packh(a2s[(e*32 + d0)*2 + 1], a2s[(e*32 + d0 + 1)*2 + 1]);
        }
    }
    int sd = t >> 3, sc4 = (t & 7) << 2;
    for (int tile = 0; tile < 8; ++tile){
        int nb = n0 + (tile << 6);
        __syncthreads();
        {
            size_t g2 = cbase2 + (size_t)sd*8192 + (nb >> 1) + sc4;
            *(uint4*)&lds[sd*36 + sc4]         = *(const uint4*)&spR[g2];
            *(uint4*)&lds[32*36 + sd*36 + sc4] = *(const uint4*)&spI[g2];
        }
        __syncthreads();
        int colb = (wave << 4) + l15;
        int cb2 = colb >> 1; bool codd = colb & 1;
        FU16 Xr, Xi, Xn;
        #pragma unroll
        for (int p = 0; p < 4; ++p){
            int d0 = (quad << 3) + (p << 1);
            unsigned e0 = lds[d0*36 + cb2], e1 = lds[(d0+1)*36 + cb2];
            Xr.u[p] = codd ? ((e0 >> 16) | (e1 & 0xFFFF0000u)) : ((e0 & 0xFFFFu) | (e1 << 16));
            e0 = lds[32*36 + d0*36 + cb2]; e1 = lds[32*36 + (d0+1)*36 + cb2];
            Xi.u[p] = codd ? ((e0 >> 16) | (e1 & 0xFFFF0000u)) : ((e0 & 0xFFFFu) | (e1 << 16));
            Xn.u[p] = Xi.u[p] ^ 0x80008000u;
        }
        #pragma unroll
        for (int et = 0; et < 2; ++et){
            f32x4 ar = (f32x4){0,0,0,0}, ai = (f32x4){0,0,0,0};
            ar = __builtin_amdgcn_mfma_f32_16x16x32_f16(Ar[et].v, Xr.v, ar, 0, 0, 0);
            ar = __builtin_amdgcn_mfma_f32_16x16x32_f16(Ai[et].v, Xn.v, ar, 0, 0, 0);
            ai = __builtin_amdgcn_mfma_f32_16x16x32_f16(Ar[et].v, Xi.v, ai, 0, 0, 0);
            ai = __builtin_amdgcn_mfma_f32_16x16x32_f16(Ai[et].v, Xr.v, ai, 0, 0, 0);
            #pragma unroll
            for (int r = 0; r < 4; ++r){
                int e = (et << 4) + (quad << 2) + r;
                om[cbase2*2 + (size_t)e*NFFT + nb + colb] = packh(ar[r], ai[r]);
            }
        }
    }
}

// ---------- K5: fused 16384-pt inverse FFT + abs per row; fp16-packed complex in, f16 out (packed pairs) ----------
__global__ __launch_bounds__(1024, 8) void k_ifft_n(const unsigned* __restrict__ in, unsigned* __restrict__ outp){
    __shared__ unsigned sp[128*129];
    int lane = threadIdx.x & 63, wave = threadIdx.x >> 6;
    size_t rb = (size_t)blockIdx.x * NFFT;
    TwI tw; make_twi(tw);
    #pragma unroll 2
    for (int it = 0; it < 8; ++it){
        int jw = (wave << 3) + it;
        size_t base = rb + ((size_t)jw << 7);
        float a0, b0, a1, b1;
        unpackh(in[base + lane], a0, b0);
        unpackh(in[base + lane + 64], a1, b1);
        dit128t(tw, a0, b0, a1, b1);
        int kw = rev7(jw);
        float sn, cs;
        sincos_rev((float)(lane * kw) * 6.103515625e-05f, sn, cs);
        float r = a0*cs - b0*sn, i2 = a0*sn + b0*cs;
        sp[lane*129 + jw] = packh(r, i2);
        sincos_rev((float)((lane + 64) * kw) * 6.103515625e-05f, sn, cs);
        r = a1*cs - b1*sn; i2 = a1*sn + b1*cs;
        sp[(lane+64)*129 + jw] = packh(r, i2);
    }
    __syncthreads();
    float av0[8], av1[8];
    #pragma unroll
    for (int it = 0; it < 8; ++it){
        int pw = (wave << 3) + it;
        float a0, b0, a1, b1;
        unpackh(sp[pw*129 + lane],      a0, b0);
        unpackh(sp[pw*129 + lane + 64], a1, b1);
        dit128t(tw, a0, b0, a1, b1);
        av0[it] = sqrtf(a0*a0 + b0*b0);
        av1[it] = sqrtf(a1*a1 + b1*b1);
    }
    __syncthreads();
    // transpose via LDS at half width: u32 holds f16 pair of adjacent columns (pw, pw+1)
    #pragma unroll
    for (int p = 0; p < 4; ++p){
        sp[lane*65 + (wave << 2) + p]      = packh(av0[2*p], av0[2*p+1]);
        sp[(lane+64)*65 + (wave << 2) + p] = packh(av1[2*p], av1[2*p+1]);
    }
    __syncthreads();
    int row = threadIdx.x >> 3, cb = (threadIdx.x & 7) << 3;
    unsigned* ob = outp + ((size_t)blockIdx.x << 13) + row*64 + cb;
    const unsigned* s = &sp[row*65 + cb];
    *(uint4*)(ob)     = make_uint4(s[0], s[1], s[2], s[3]);
    *(uint4*)(ob + 4) = make_uint4(s[4], s[5], s[6], s[7]);
}

// ---------- K6: gating, IN-PLACE on fp16 half-planes ----------
__global__ __launch_bounds__(256) void k_gate(unsigned* spR, unsigned* spI,
                                              const float* __restrict__ w1, const float* __restrict__ b1,
                                              const float* __restrict__ bg, const float* __restrict__ bb_,
                                              const float* __restrict__ bm, const float* __restrict__ bv,
                                              const float* __restrict__ w2, const float* __restrict__ b2){
    __shared__ float w1T[256*17];
    __shared__ float w2s[256*16];
    __shared__ float yred[256*17];
    int t = threadIdx.x, g = t >> 6, col = t & 63;
    #pragma unroll
    for (int i = 0; i < 16; ++i) w1T[t*17 + i] = w1[i*256 + t];
    {
        const float4* s4 = (const float4*)w2; float4* d4 = (float4*)w2s;
        #pragma unroll
        for (int i = 0; i < 4; ++i) d4[i*256 + t] = s4[i*256 + t];
    }
    __syncthreads();
    int b = blockIdx.x >> 8;
    int n = ((blockIdx.x & 255) << 6) + col;
    int odd = n & 1;
    size_t base2 = (((size_t)b << 8) << 13) + (n >> 1);
    float y[16];
    #pragma unroll
    for (int r = 0; r < 16; ++r) y[r] = 0.f;
    for (int c = g << 6; c < (g << 6) + 64; ++c){
        float lo, hi; unpackh(spR[base2 + ((size_t)c << 13)], lo, hi);
        float xr = odd ? hi : lo;
        #pragma unroll
        for (int r = 0; r < 16; ++r) y[r] += w1T[c*17 + r] * xr;
    }
    #pragma unroll
    for (int r = 0; r < 16; ++r) yred[t*17 + r] = y[r];
    __syncthreads();
    #pragma unroll
    for (int r = 0; r < 16; ++r){
        float v = yred[col*17 + r] + yred[(col+64)*17 + r]
                + yred[(col+128)*17 + r] + yred[(col+192)*17 + r] + b1[r];
        v = (v - bm[r]) * rsqrtf(bv[r] + 1e-5f) * bg[r] + bb_[r];
        y[r] = fmaxf(v, 0.f);
    }
    for (int o = g << 6; o < (g << 6) + 64; ++o){
        float s = b2[o];
        #pragma unroll
        for (int r = 0; r < 16; ++r) s += w2s[o*16 + r] * y[r];
        float gg = 1.f / (1.f + __expf(-s)) * 6.103515625e-05f;   // sigmoid * 1/16384
        float ggN = shfx1(gg);
        size_t mi = base2 + ((size_t)o << 13);
        if (!odd){
            float lo, hi; unpackh(spR[mi], lo, hi);
            spR[mi] = packh(gg*lo, ggN*hi);
        } else {
            float lo, hi; unpackh(spI[mi], lo, hi);
            spI[mi] = packh(ggN*lo, gg*hi);
        }
    }
}

// ---------- K7: fused ifft2 per image + abs -> f16 (packed pairs) into Cat1 ----------
__global__ __launch_bounds__(1024, 8) void k_ifft2_gate(const unsigned* __restrict__ spR,
                                                        const unsigned* __restrict__ spI,
                                                        unsigned* __restrict__ outp){
    __shared__ unsigned sp[128*129];
    int lane = threadIdx.x & 63, wave = threadIdx.x >> 6;
    TwI tw; make_twi(tw);
    size_t ib = (size_t)blockIdx.x * NFFT;
    #pragma unroll 2
    for (int it = 0; it < 8; ++it){
        int jw = (wave << 3) + it;
        size_t m = (ib + ((size_t)jw << 7)) >> 1;
        int k = lane >> 1; bool od = lane & 1;
        float lo, hi, a0, b0, a1, b1;
        unpackh(spR[m + k], lo, hi);      a0 = od ? hi : lo;
        unpackh(spI[m + k], lo, hi);      b0 = od ? hi : lo;
        unpackh(spR[m + 32 + k], lo, hi); a1 = od ? hi : lo;
        unpackh(spI[m + 32 + k], lo, hi); b1 = od ? hi : lo;
        dit128t(tw, a0, b0, a1, b1);
        sp[lane*129 + jw]      = packh(a0, b0);
        sp[(lane+64)*129 + jw] = packh(a1, b1);
    }
    __syncthreads();
    #pragma unroll 2
    for (int it = 0; it < 8; ++it){
        int ph = (wave << 3) + it;
        float a0, b0, a1, b1;
        unpackh(sp[ph*129 + lane],      a0, b0);
        unpackh(sp[ph*129 + lane + 64], a1, b1);
        dit128t(tw, a0, b0, a1, b1);
        float v0 = sqrtf(a0*a0 + b0*b0), v1 = sqrtf(a1*a1 + b1*b1);
        float p0 = shfx1(v0), p1 = shfx1(v1);
        if (!(lane & 1)){
            size_t o2 = ((size_t)blockIdx.x << 13) + (ph << 6);
            outp[o2 + (lane >> 1)]      = packh(v0, p0);
            outp[o2 + 32 + (lane >> 1)] = packh(v1, p1);
        }
    }
}

// ---------- K7b: pack pw into f16 pairs (along k) ----------
__global__ __launch_bounds__(256) void k_pw_cvt(const float* __restrict__ pw, unsigned* __restrict__ pwp){
    int i = (blockIdx.x << 10) + (threadIdx.x << 2);
    float4 v = *(const float4*)(pw + i);
    uint2 o;
    o.x = packh(v.x, v.y); o.y = packh(v.z, v.w);
    *(uint2*)(pwp + (i >> 1)) = o;
}

// ---------- K8: projection via f16 MFMA, single product per fragment ----------
__global__ __launch_bounds__(256) void k_proj(const unsigned* __restrict__ cat0, const unsigned* __restrict__ cat1,
                                              const unsigned* __restrict__ pwp, float* __restrict__ out){
    __shared__ unsigned As[128*17];   // [o][k2] f16 pairs along k, stride 17
    __shared__ unsigned Bs[32*65];    // [k][n2] f16 pairs along n, stride 65
    int t = threadIdx.x, lane = t & 63, wave = t >> 6;
    int quad = lane >> 4, l15 = lane & 15;
    int b  = blockIdx.x >> 8;
    int mo = (blockIdx.x >> 7) & 1;
    int nt = blockIdx.x & 127;
    int n0 = nt << 7;
    int n0_2 = nt << 6;
    int wr = (wave >> 1) << 6;
    int wc = (wave & 1) << 6;

    f32x4 acc[4][4];
    #pragma unroll
    for (int i = 0; i < 4; ++i)
        #pragma unroll
        for (int j = 0; j < 4; ++j) acc[i][j] = (f32x4){0.f,0.f,0.f,0.f};

    int ao = t >> 1, ak = (t & 1) << 3;
    int bk = t >> 3, bn8 = (t & 7) << 3;
    int par = l15 & 1;

    for (int ks = 0; ks < 16; ++ks){
        __syncthreads();
        {
            const unsigned* ap = pwp + (size_t)((mo << 7) + ao)*256 + (ks << 4) + ak;
            #pragma unroll
            for (int i = 0; i < 8; ++i) As[ao*17 + ak + i] = ap[i];
        }
        {
            int q = (ks << 5) + bk;
            const unsigned* srow = (q < 256) ? (cat0 + (size_t)((b << 8) + q) * 8192)
                                             : (cat1 + (size_t)((b << 8) + q - 256) * 8192);
            const unsigned* sp_ = srow + n0_2 + bn8;
            *(uint4*)&Bs[bk*65 + bn8]     = *(const uint4*)sp_;
            *(uint4*)&Bs[bk*65 + bn8 + 4] = *(const uint4*)(sp_ + 4);
        }
        __syncthreads();
        FU16 Af[4], Bf[4];
        #pragma unroll
        for (int mi = 0; mi < 4; ++mi){
            const unsigned* ap = &As[(wr + (mi << 4) + l15)*17 + (quad << 2)];
            #pragma unroll
            for (int p = 0; p < 4; ++p) Af[mi].u[p] = ap[p];
        }
        #pragma unroll
        for (int ni = 0; ni < 4; ++ni){
            int n2 = (wc + (ni << 4) + l15) >> 1;
            #pragma unroll
            for (int p = 0; p < 4; ++p){
                unsigned e0 = Bs[((quad << 3) + 2*p)*65 + n2];
                unsigned e1 = Bs[((quad << 3) + 2*p + 1)*65 + n2];
                Bf[ni].u[p] = par ? ((e0 >> 16) | (e1 & 0xFFFF0000u))
                                  : ((e0 & 0xFFFFu) | (e1 << 16));
            }
        }
        #pragma unroll
        for (int mi = 0; mi < 4; ++mi)
            #pragma unroll
            for (int ni = 0; ni < 4; ++ni)
                acc[mi][ni] = __builtin_amdgcn_mfma_f32_16x16x32_f16(Af[mi].v, Bf[ni].v, acc[mi][ni], 0, 0, 0);
    }
    size_t obase = (size_t)((b << 8) + (mo << 7));
    #pragma unroll
    for (int mi = 0; mi < 4; ++mi)
        #pragma unroll
        for (int ni = 0; ni < 4; ++ni){
            int o_ = wr + (mi << 4) + (quad << 2);
            int n_ = n0 + wc + (ni << 4) + l15;
            float* op = out + (obase + o_)*NFFT + n_;
            #pragma unroll
            for (int r = 0; r < 4; ++r) op[(size_t)r*NFFT] = acc[mi][ni][r];
        }
}

// ---------- host ----------
extern "C" void kernel_launch(void* const* d_in, const int* in_sizes, int n_in,
                              void* d_out, int out_size, void* d_ws, size_t ws_size,
                              hipStream_t stream) {
    const float* x    = (const float*)d_in[0];
    const float* temp = (const float*)d_in[1];
    const float* w1   = (const float*)d_in[2];
    const float* b1   = (const float*)d_in[3];
    const float* bg   = (const float*)d_in[4];
    const float* bb_  = (const float*)d_in[5];
    const float* bm   = (const float*)d_in[6];
    const float* bv   = (const float*)d_in[7];
    const float* w2   = (const float*)d_in[8];
    const float* b2   = (const float*)d_in[9];
    const float* pw   = (const float*)d_in[10];
    float* out = (float*)d_out;

    float* ws = (float*)d_ws;
    unsigned* SpecR = (unsigned*)ws;             // fp16 re half-plane, NP/2 u32
    unsigned* SpecI = SpecR + (NP >> 1);         // fp16 im half-plane
    unsigned* Ecat  = (unsigned*)(ws + NP);      // Gpart scratch -> mix out (fp16 cplx), read by ifft_n
    unsigned* Cat0  = (unsigned*)(ws + 2*NP);    // ifft_n out, f16 pairs (8.4M u32)
    unsigned* Cat1  = Cat0 + 8388608;            // ifft2_gate out, f16 pairs (8.4M u32)
    float* norm2 = ws + 3*NP;                    // 1024
    float* G     = norm2 + 1024;                 // 65536
    float* attn2 = G + 65536;                    // 65536
    unsigned* pwpack = (unsigned*)(attn2 + 65536);  // 65536 u32 (f16 pairs)
    float* Gpart = (float*)Ecat;                 // 8 MB scratch, dead until k_mix

    size_t need = (3*NP + 1024 + 65536 + 65536 + 131072) * sizeof(float);
    if (ws_size < need) return;

    k_pw_cvt<<<128, 256, 0, stream>>>(pw, pwpack);
    k_fft2_fwd<<<1024, 1024, 0, stream>>>(x, SpecR, SpecI, norm2);
    k_gram<<<1024, 256, 0, stream>>>(SpecR, SpecI, Gpart);
    k_gram_red<<<256, 256, 0, stream>>>(Gpart, G);
    k_attn<<<32, 256, 0, stream>>>(G, norm2, temp, attn2);
    k_mix<<<1024, 256, 0, stream>>>(SpecR, SpecI, attn2, Ecat);
    k_ifft_n<<<1024, 1024, 0, stream>>>(Ecat, Cat0);
    k_gate<<<1024, 256, 0, stream>>>(SpecR, SpecI, w1, b1, bg, bb_, bm, bv, w2, b2);
    k_ifft2_gate<<<1024, 1024, 0, stream>>>(SpecR, SpecI, Cat1);
    k_proj<<<1024, 256, 0, stream>>>(Cat0, Cat1, pwpack, out);
    (void)in_sizes; (void)n_in; (void)out_size; (void)ws_size;
}